// Round 8
// baseline (524.730 us; speedup 1.0000x reference)
//
#include <hip/hip_runtime.h>
#include <hip/hip_bf16.h>

typedef __hip_bfloat16 bf16;
typedef __attribute__((ext_vector_type(8))) short bf8_t;  // 8 bf16 (4 VGPR)
typedef __attribute__((ext_vector_type(4))) float f4_t;

__device__ __forceinline__ float b2f(bf16 x) { return __bfloat162float(x); }

__device__ __forceinline__ float ldany(const void* p, size_t i, int isbf) {
    return isbf ? b2f(((const bf16*)p)[i]) : ((const float*)p)[i];
}

// fp32 -> bf16 (RTN-even), bit pattern as short
__device__ __forceinline__ short f2b(float f) {
    unsigned u = __builtin_bit_cast(unsigned, f);
    u += 0x7fffu + ((u >> 16) & 1u);
    return (short)(u >> 16);
}

// ---------------------------------------------------------------- dtype detect
__global__ __launch_bounds__(64) void k_detect(const void* __restrict__ dec,
                                               int* __restrict__ flag) {
    __shared__ int cnt;
    if (threadIdx.x == 0) cnt = 0;
    __syncthreads();
    int bad = 0;
    for (int i = threadIdx.x; i < 256; i += 64) {
        float f = b2f(((const bf16*)dec)[i]);
        float a = fabsf(f);
        if (!(a < 1e10f) || (a != 0.f && a < 1e-20f)) bad++;
    }
    atomicAdd(&cnt, bad);
    __syncthreads();
    if (threadIdx.x == 0) *flag = (cnt >= 3) ? 0 : 1;  // 0=fp32, 1=bf16
}

// ---------------------------------------------------------------- weight prep
// W (K,N) fp32/bf16 -> Wt (N,K) bf16. One-time per launch; makes each 512x512
// weight slab 0.5 MB (L2-resident on every XCD) and enables ds_read_b128
// B-fragments in the GEMM.
struct WT13 {
    const void* src[13];
};

__global__ __launch_bounds__(256) void k_wtrans(WT13 w, short* __restrict__ dst,
                                                int K, int N,
                                                const int* __restrict__ flagp) {
    __shared__ float T[32][33];
    int isbf = *flagp;
    const void* src = w.src[blockIdx.z];
    short* d = dst + (size_t)blockIdx.z * K * N;
    int nb = blockIdx.x * 32, kb = blockIdx.y * 32;
    int col = threadIdx.x & 31, row0 = threadIdx.x >> 5;
#pragma unroll
    for (int i = 0; i < 4; i++) {
        int r = row0 + i * 8;
        T[r][col] = ldany(src, (size_t)(kb + r) * N + nb + col, isbf);
    }
    __syncthreads();
#pragma unroll
    for (int i = 0; i < 4; i++) {
        int r = row0 + i * 8;
        d[(size_t)(nb + r) * K + kb + col] = f2b(T[col][r]);
    }
}

// ---------------------------------------------------------------- MFMA GEMM
// 64x64 tile, BK=64, 4 waves x (64m x 16n), acc=16 VGPR. A: fp32 ws or
// external (register-staged, fp32->bf16). B: pre-transposed bf16 Wt (N,K) —
// 16B vector loads, [n][k] LDS rows (stride 72), b-frag = 1x ds_read_b128.
struct GArgs {
    const void* W[4];   // bf16 Wt (Nper,K)
    const void* Bias[4];
    float scale[4];
    float* Out[4];
};

template <int AEXT>
__global__ __launch_bounds__(256, 4) void k_gemm_mfma(
    const void* __restrict__ Av, GArgs g, const float* __restrict__ Res,
    const void* __restrict__ ResAny, int Nper, int K, int relu,
    const int* __restrict__ flagp) {
    constexpr int ASTR = 72;
    constexpr int BSTR = 72;
    __shared__ __align__(16) short As[64 * ASTR];
    __shared__ __align__(16) short Bs[64 * BSTR];
    int isbf = *flagp;
    int tid = threadIdx.x;
    int wave = tid >> 6, lane = tid & 63;
    int quad = lane >> 4, l16 = lane & 15;
    int mb = blockIdx.y * 64;
    int nbg = blockIdx.x * 64;
    int slot = nbg / Nper;
    int nb = nbg - slot * Nper;
    const short* Wt = (const short*)g.W[slot];
    int wn = wave * 16;
    f4_t acc[4] = {};

    for (int k0 = 0; k0 < K; k0 += 64) {
        // ---- issue all global loads first (stay in flight) ----
        float4 arf[4];
        ushort4 arb[4];
        int4 brv[2];
        if (AEXT && isbf) {
#pragma unroll
            for (int i = 0; i < 4; i++) {
                int chunk = tid + 256 * i;
                int m = chunk >> 4, kc = (chunk & 15) * 4;
                arb[i] = *(const ushort4*)((const unsigned short*)Av +
                                           (size_t)(mb + m) * K + k0 + kc);
            }
        } else {
#pragma unroll
            for (int i = 0; i < 4; i++) {
                int chunk = tid + 256 * i;
                int m = chunk >> 4, kc = (chunk & 15) * 4;
                arf[i] = *(const float4*)((const float*)Av +
                                          (size_t)(mb + m) * K + k0 + kc);
            }
        }
#pragma unroll
        for (int i = 0; i < 2; i++) {
            int chunk = tid + 256 * i;  // 0..511
            int nl = chunk >> 3, k8 = (chunk & 7) * 8;
            brv[i] = *(const int4*)(Wt + (size_t)(nb + nl) * K + k0 + k8);
        }
        __syncthreads();  // previous iteration's frag reads done
        // ---- stage to LDS ----
#pragma unroll
        for (int i = 0; i < 4; i++) {
            int chunk = tid + 256 * i;
            int m = chunk >> 4, kc = (chunk & 15) * 4;
            short4 s;
            if (AEXT && isbf) {
                s.x = (short)arb[i].x; s.y = (short)arb[i].y;
                s.z = (short)arb[i].z; s.w = (short)arb[i].w;
            } else {
                s.x = f2b(arf[i].x); s.y = f2b(arf[i].y);
                s.z = f2b(arf[i].z); s.w = f2b(arf[i].w);
            }
            *(short4*)&As[m * ASTR + kc] = s;
        }
#pragma unroll
        for (int i = 0; i < 2; i++) {
            int chunk = tid + 256 * i;
            int nl = chunk >> 3, k8 = (chunk & 7) * 8;
            *(int4*)&Bs[nl * BSTR + k8] = brv[i];
        }
        __syncthreads();
        // ---- fragments + MFMA (two K=32 halves) ----
#pragma unroll
        for (int half = 0; half < 2; half++) {
            bf8_t b = *(const bf8_t*)&Bs[(wn + l16) * BSTR + half * 32 +
                                         quad * 8];
#pragma unroll
            for (int fi = 0; fi < 4; fi++) {
                bf8_t a = *(const bf8_t*)&As[(fi * 16 + l16) * ASTR +
                                             half * 32 + quad * 8];
                acc[fi] = __builtin_amdgcn_mfma_f32_16x16x32_bf16(a, b,
                                                                  acc[fi],
                                                                  0, 0, 0);
            }
        }
    }
    const void* Bias = g.Bias[slot];
    float scale = g.scale[slot];
    float* O = g.Out[slot];
    int n = nb + wn + l16;
    float bia = ldany(Bias, n, isbf);
#pragma unroll
    for (int fi = 0; fi < 4; fi++) {
#pragma unroll
        for (int r = 0; r < 4; r++) {
            int m = mb + fi * 16 + quad * 4 + r;
            float v = (acc[fi][r] + bia) * scale;
            if (relu) v = fmaxf(v, 0.f);
            if (Res) v += Res[(size_t)m * Nper + n];
            if (ResAny) v += ldany(ResAny, (size_t)m * Nper + n, isbf);
            O[(size_t)m * Nper + n] = v;
        }
    }
}

// ---------------------------------------------------------------- pattn
__global__ __launch_bounds__(256) void k_pattn(const float* __restrict__ pcp,
                                               const float* __restrict__ pqp,
                                               float* __restrict__ pattn) {
    __shared__ float pcs[8][65];
    __shared__ float pqs[32][65];
    int bh = blockIdx.y, tb = blockIdx.x;
    int b = bh >> 3, h = bh & 7;
    for (int lin = threadIdx.x; lin < 512; lin += 256) {
        int tt = lin >> 6, dd = lin & 63;
        pcs[tt][dd] = pcp[((size_t)b * 1024 + tb * 8 + tt) * 512 + h * 64 + dd];
    }
    for (int lin = threadIdx.x; lin < 2048; lin += 256) {
        int e = lin >> 6, dd = lin & 63;
        pqs[e][dd] = pqp[(size_t)(b * 32 + e) * 512 + h * 64 + dd];
    }
    __syncthreads();
    int e = threadIdx.x & 31, tt = threadIdx.x >> 5;
    float s = 0.f;
#pragma unroll
    for (int dd = 0; dd < 64; dd++) s += pcs[tt][dd] * pqs[e][dd];
    float r = (s > 0.f) ? (s + log2f(1.f + exp2f(-s))) : log2f(1.f + exp2f(s));
    pattn[((size_t)bh * 1024 + tb * 8 + tt) * 32 + e] = r;
}

// ---------------------------------------------------------------- ECA phase 1
__global__ __launch_bounds__(256) void k_eca1(
    const float* __restrict__ kp, const float* __restrict__ vp,
    const float* __restrict__ pattn, float* __restrict__ L1,
    float* __restrict__ L2) {
    __shared__ float Ks[64][65];
    __shared__ float Vs[64][65];
    __shared__ float Ps[64][33];
    int bh = blockIdx.y, c = blockIdx.x;
    int b = bh >> 3, h = bh & 7;
    size_t rowbase = (size_t)b * 1024 + c * 64;
    for (int ch = threadIdx.x; ch < 1024; ch += 256) {
        int s = ch >> 4, d4 = (ch & 15) * 4;
        size_t gidx = (rowbase + s) * 512 + h * 64 + d4;
        float4 k4 = *(const float4*)&kp[gidx];
        float4 v4 = *(const float4*)&vp[gidx];
        Ks[s][d4] = k4.x; Ks[s][d4 + 1] = k4.y;
        Ks[s][d4 + 2] = k4.z; Ks[s][d4 + 3] = k4.w;
        Vs[s][d4] = v4.x; Vs[s][d4 + 1] = v4.y;
        Vs[s][d4 + 2] = v4.z; Vs[s][d4 + 3] = v4.w;
    }
    for (int ch = threadIdx.x; ch < 512; ch += 256) {
        int s = ch >> 3, e4 = (ch & 7) * 4;
        float4 p4 = *(const float4*)&pattn[((size_t)bh * 1024 + c * 64 + s) * 32 + e4];
        Ps[s][e4] = p4.x; Ps[s][e4 + 1] = p4.y;
        Ps[s][e4 + 2] = p4.z; Ps[s][e4 + 3] = p4.w;
    }
    __syncthreads();
    size_t lbase = ((size_t)bh * 16 + c) * 2048;
    {
        int e = threadIdx.x & 31, dd0 = (threadIdx.x >> 5) * 8;
        float acc[8] = {};
        for (int s = 0; s < 64; s++) {
            float ps = Ps[s][e];
#pragma unroll
            for (int j = 0; j < 8; j++) acc[j] += Ks[s][dd0 + j] * ps;
        }
#pragma unroll
        for (int j = 0; j < 8; j++) L1[lbase + (dd0 + j) * 32 + e] = acc[j];
    }
    {
        int dd = threadIdx.x & 63, e0 = (threadIdx.x >> 6) * 8;
        float acc[8] = {};
        for (int s = 0; s < 64; s++) {
            float vv = Vs[s][dd];
#pragma unroll
            for (int j = 0; j < 8; j++) acc[j] += Ps[s][e0 + j] * vv;
        }
#pragma unroll
        for (int j = 0; j < 8; j++) L2[lbase + (e0 + j) * 64 + dd] = acc[j];
    }
}

// ---------------------------------------------------------------- chunk scan
__global__ __launch_bounds__(256) void k_scan(float* __restrict__ L1,
                                              float* __restrict__ L2) {
    int gid = blockIdx.x * 256 + threadIdx.x;  // 32768 = 16 bh * 2048
    int bh = gid >> 11, lin = gid & 2047;
    size_t base = (size_t)bh * 16 * 2048 + lin;
    float run = 0.f;
#pragma unroll
    for (int c = 0; c < 16; c++) {
        float v = L1[base + c * 2048];
        L1[base + c * 2048] = run;
        run += v;
    }
    run = 0.f;
#pragma unroll
    for (int c = 0; c < 16; c++) {
        float v = L2[base + c * 2048];
        L2[base + c * 2048] = run;
        run += v;
    }
}

// ---------------------------------------------------------------- ECA phase 3
__global__ __launch_bounds__(512) void k_eca3(
    const float* __restrict__ qp, const float* __restrict__ kp,
    const float* __restrict__ vp, const float* __restrict__ pattn,
    const float* __restrict__ L1s, const float* __restrict__ L2s,
    float* __restrict__ attn) {
    __shared__ float R0[64][65];
    __shared__ float R1[64][65];
    __shared__ float Ps[64][33];
    __shared__ float SS[2112];
    __shared__ float Pr[64][33];
    int bh = blockIdx.y, c = blockIdx.x;
    int b = bh >> 3, h = bh & 7;
    size_t rowbase = (size_t)b * 1024 + c * 64;
    int tid = threadIdx.x;
    for (int ch = tid; ch < 1024; ch += 512) {
        int t = ch >> 4, d4 = (ch & 15) * 4;
        size_t gidx = (rowbase + t) * 512 + h * 64 + d4;
        float4 q4 = *(const float4*)&qp[gidx];
        float4 k4 = *(const float4*)&kp[gidx];
        R0[t][d4] = q4.x; R0[t][d4 + 1] = q4.y;
        R0[t][d4 + 2] = q4.z; R0[t][d4 + 3] = q4.w;
        R1[t][d4] = k4.x; R1[t][d4 + 1] = k4.y;
        R1[t][d4 + 2] = k4.z; R1[t][d4 + 3] = k4.w;
    }
    if (tid < 512) {
        int ch = tid;
        {
            int t = ch >> 3, e4 = (ch & 7) * 4;
            float4 p4 = *(const float4*)&pattn[((size_t)bh * 1024 + c * 64 + t) * 32 + e4];
            Ps[t][e4] = p4.x; Ps[t][e4 + 1] = p4.y;
            Ps[t][e4 + 2] = p4.z; Ps[t][e4 + 3] = p4.w;
        }
        {
            float4 s4 = *(const float4*)&L1s[((size_t)bh * 16 + c) * 2048 + ch * 4];
            int dd = ch >> 3, e4 = (ch & 7) * 4;
            SS[dd * 33 + e4] = s4.x; SS[dd * 33 + e4 + 1] = s4.y;
            SS[dd * 33 + e4 + 2] = s4.z; SS[dd * 33 + e4 + 3] = s4.w;
        }
    }
    __syncthreads();
    int tx = tid & 15, ty = tid >> 4;
    float a1r[2][4] = {};
    float qs1[2][2] = {};
    for (int dd = 0; dd < 64; dd++) {
        float q2[2], k4[4];
#pragma unroll
        for (int i = 0; i < 2; i++) q2[i] = R0[ty * 2 + i][dd];
#pragma unroll
        for (int j = 0; j < 4; j++) k4[j] = R1[tx * 4 + j][dd];
#pragma unroll
        for (int i = 0; i < 2; i++)
#pragma unroll
            for (int j = 0; j < 4; j++) a1r[i][j] += q2[i] * k4[j];
        float s1a = SS[dd * 33 + tx * 2], s1b = SS[dd * 33 + tx * 2 + 1];
#pragma unroll
        for (int i = 0; i < 2; i++) {
            qs1[i][0] += q2[i] * s1a;
            qs1[i][1] += q2[i] * s1b;
        }
    }
    __syncthreads();
#pragma unroll
    for (int i = 0; i < 2; i++) {
#pragma unroll
        for (int j = 0; j < 4; j++) R0[ty * 2 + i][tx * 4 + j] = a1r[i][j];
        Pr[ty * 2 + i][tx * 2] = qs1[i][0];
        Pr[ty * 2 + i][tx * 2 + 1] = qs1[i][1];
    }
    for (int ch = tid; ch < 1024; ch += 512) {
        int t = ch >> 4, d4 = (ch & 15) * 4;
        float4 v4 = *(const float4*)&vp[(rowbase + t) * 512 + h * 64 + d4];
        R1[t][d4] = v4.x; R1[t][d4 + 1] = v4.y;
        R1[t][d4 + 2] = v4.z; R1[t][d4 + 3] = v4.w;
    }
    __syncthreads();
    {
        int e = tid & 31, t0 = (tid >> 5) * 4;
        for (int k2 = 0; k2 < 4; k2++) {
            int t = t0 + k2;
            float s = Pr[t][e];
            for (int s2 = 0; s2 <= t; s2++) s += R0[t][s2] * Ps[s2][e];
            Pr[t][e] = s / (float)(c * 64 + t + 1);
        }
    }
    __syncthreads();
    if (tid < 64) {
        float m = -1e30f;
        for (int e = 0; e < 32; e++) m = fmaxf(m, Pr[tid][e]);
        float sum = 0.f;
        for (int e = 0; e < 32; e++) {
            float ex = expf(Pr[tid][e] - m);
            Pr[tid][e] = ex;
            sum += ex;
        }
        float inv = 1.f / sum;
        for (int e = 0; e < 32; e++) Pr[tid][e] *= inv;
    } else if (tid >= 128) {
        for (int ch = tid - 128; ch < 512; ch += 384) {
            float4 s4 = *(const float4*)&L2s[((size_t)bh * 16 + c) * 2048 + ch * 4];
            int e = ch >> 4, d4 = (ch & 15) * 4;
            SS[e * 65 + d4] = s4.x; SS[e * 65 + d4 + 1] = s4.y;
            SS[e * 65 + d4 + 2] = s4.z; SS[e * 65 + d4 + 3] = s4.w;
        }
    }
    __syncthreads();
    float a2r[2][4] = {};
    float ps2[2][4] = {};
    for (int e = 0; e < 32; e++) {
        float p2[2], b4[4], v4[4];
#pragma unroll
        for (int i = 0; i < 2; i++) p2[i] = Pr[ty * 2 + i][e];
#pragma unroll
        for (int j = 0; j < 4; j++) {
            b4[j] = Ps[tx * 4 + j][e];
            v4[j] = SS[e * 65 + tx * 4 + j];
        }
#pragma unroll
        for (int i = 0; i < 2; i++)
#pragma unroll
            for (int j = 0; j < 4; j++) {
                a2r[i][j] += p2[i] * b4[j];
                ps2[i][j] += p2[i] * v4[j];
            }
    }
    __syncthreads();
#pragma unroll
    for (int i = 0; i < 2; i++)
#pragma unroll
        for (int j = 0; j < 4; j++) R0[ty * 2 + i][tx * 4 + j] = a2r[i][j];
    __syncthreads();
#pragma unroll
    for (int i = 0; i < 2; i++) {
        int t = ty * 2 + i;
        float acch[4];
#pragma unroll
        for (int j = 0; j < 4; j++) acch[j] = ps2[i][j];
        for (int s = 0; s <= t; s++) {
            float a2v = R0[t][s];
#pragma unroll
            for (int j = 0; j < 4; j++) acch[j] += a2v * R1[s][tx * 4 + j];
        }
        float inv = 1.f / (float)(c * 64 + t + 1);
#pragma unroll
        for (int j = 0; j < 4; j++)
            attn[(rowbase + t) * 512 + h * 64 + tx * 4 + j] = acch[j] * inv;
    }
}

// ---------------------------------------------------------------- MHA1 scores
__global__ __launch_bounds__(256) void k_mha1_scores(
    const float* __restrict__ pkq, const float* __restrict__ pkk,
    float* __restrict__ sbuf) {
    __shared__ float Qs[32][65];
    __shared__ float Ks[64][65];
    int bh = blockIdx.y, kb = blockIdx.x;
    int b = bh >> 3, h = bh & 7;
    for (int lin = threadIdx.x; lin < 2048; lin += 256) {
        int i = lin >> 6, dd = lin & 63;
        Qs[i][dd] = pkq[(size_t)(b * 32 + i) * 512 + h * 64 + dd];
    }
    for (int lin = threadIdx.x; lin < 4096; lin += 256) {
        int kk = lin >> 6, dd = lin & 63;
        Ks[kk][dd] = pkk[((size_t)b * 1024 + kb * 64 + kk) * 512 + h * 64 + dd];
    }
    __syncthreads();
    int kk = threadIdx.x & 63, i0 = (threadIdx.x >> 6) * 8;
    for (int ii = 0; ii < 8; ii++) {
        int i = i0 + ii;
        float s = 0.f;
#pragma unroll
        for (int dd = 0; dd < 64; dd++) s += Qs[i][dd] * Ks[kk][dd];
        sbuf[((size_t)bh * 32 + i) * 1024 + kb * 64 + kk] = s;
    }
}

// ---------------------------------------------------------------- row softmax
__global__ __launch_bounds__(256) void k_softmax_rows(float* __restrict__ buf,
                                                      int cols) {
    int wave = threadIdx.x >> 6, lane = threadIdx.x & 63;
    int row = blockIdx.x * 4 + wave;
    float* p = buf + (size_t)row * cols;
    int per = cols >> 6;
    float m = -1e30f;
    for (int j = 0; j < per; j++) m = fmaxf(m, p[lane + 64 * j]);
#pragma unroll
    for (int off = 32; off >= 1; off >>= 1) m = fmaxf(m, __shfl_xor(m, off, 64));
    float sum = 0.f;
    for (int j = 0; j < per; j++) {
        float ex = expf(p[lane + 64 * j] - m);
        p[lane + 64 * j] = ex;
        sum += ex;
    }
#pragma unroll
    for (int off = 32; off >= 1; off >>= 1) sum += __shfl_xor(sum, off, 64);
    float inv = 1.f / sum;
    for (int j = 0; j < per; j++) p[lane + 64 * j] *= inv;
}

// ---------------------------------------------------------------- MHA1 ctx
__global__ __launch_bounds__(256) void k_mha1_ctx_p(
    const float* __restrict__ sbuf, const float* __restrict__ pkv,
    float* __restrict__ part) {
    __shared__ float Vs[64][65];
    __shared__ float Ps[32][33];
    int bh = blockIdx.y, c = blockIdx.x;
    int b = bh >> 3, h = bh & 7;
    for (int lin = threadIdx.x; lin < 4096; lin += 256) {
        int kk = lin >> 6, dd = lin & 63;
        Vs[kk][dd] = pkv[((size_t)b * 1024 + c * 64 + kk) * 512 + h * 64 + dd];
    }
    for (int lin = threadIdx.x; lin < 2048; lin += 256) {
        int i = lin >> 6, kk = lin & 63;
        Ps[i][kk] = sbuf[((size_t)bh * 32 + i) * 1024 + c * 64 + kk];
    }
    __syncthreads();
    int dd = threadIdx.x & 63, ig = threadIdx.x >> 6;
    float acc[8] = {};
    for (int kk = 0; kk < 64; kk++) {
        float vv = Vs[kk][dd];
#pragma unroll
        for (int j = 0; j < 8; j++) acc[j] += Ps[ig * 8 + j][kk] * vv;
    }
    size_t base = ((size_t)bh * 16 + c) * 2048;
#pragma unroll
    for (int j = 0; j < 8; j++) part[base + (ig * 8 + j) * 64 + dd] = acc[j];
}

__global__ __launch_bounds__(256) void k_mha1_ctx_r(
    const float* __restrict__ part, float* __restrict__ yp_raw) {
    int gid = blockIdx.x * 256 + threadIdx.x;
    int bh = gid >> 11, rem = gid & 2047;
    int i = rem >> 6, dd = rem & 63;
    float s = 0.f;
#pragma unroll
    for (int c = 0; c < 16; c++) s += part[((size_t)bh * 16 + c) * 2048 + rem];
    int b = bh >> 3, h = bh & 7;
    yp_raw[(size_t)(b * 32 + i) * 512 + h * 64 + dd] = s;
}

// ---------------------------------------------------------------- MHA2 (fused)
__global__ __launch_bounds__(256) void k_mha2(const float* __restrict__ upq,
                                              const float* __restrict__ upk,
                                              const float* __restrict__ upv,
                                              float* __restrict__ yxctx) {
    __shared__ float Ksm[32][65];
    __shared__ float Vsm[32][65];
    __shared__ float Qsm[64][65];
    __shared__ float Prm[64][33];
    int bh = blockIdx.y, c = blockIdx.x;
    int b = bh >> 3, h = bh & 7;
    for (int lin = threadIdx.x; lin < 2048; lin += 256) {
        int e = lin >> 6, dd = lin & 63;
        Ksm[e][dd] = upk[(size_t)(b * 32 + e) * 512 + h * 64 + dd];
        Vsm[e][dd] = upv[(size_t)(b * 32 + e) * 512 + h * 64 + dd];
    }
    for (int lin = threadIdx.x; lin < 4096; lin += 256) {
        int t = lin >> 6, dd = lin & 63;
        Qsm[t][dd] = upq[((size_t)b * 1024 + c * 64 + t) * 512 + h * 64 + dd];
    }
    __syncthreads();
    int row = threadIdx.x >> 2, r = threadIdx.x & 3;
    float p[8];
#pragma unroll
    for (int j = 0; j < 8; j++) {
        int e = r * 8 + j;
        float s = 0.f;
#pragma unroll
        for (int dd = 0; dd < 64; dd++) s += Qsm[row][dd] * Ksm[e][dd];
        p[j] = s;
    }
    float m = -1e30f;
#pragma unroll
    for (int j = 0; j < 8; j++) m = fmaxf(m, p[j]);
    m = fmaxf(m, __shfl_xor(m, 1, 64));
    m = fmaxf(m, __shfl_xor(m, 2, 64));
    float sum = 0.f;
#pragma unroll
    for (int j = 0; j < 8; j++) {
        p[j] = expf(p[j] - m);
        sum += p[j];
    }
    sum += __shfl_xor(sum, 1, 64);
    sum += __shfl_xor(sum, 2, 64);
    float inv = 1.f / sum;
#pragma unroll
    for (int j = 0; j < 8; j++) Prm[row][r * 8 + j] = p[j] * inv;
    __syncthreads();
    for (int jd = 0; jd < 16; jd++) {
        int dd = r * 16 + jd;
        float acc = 0.f;
#pragma unroll
        for (int e = 0; e < 32; e++) acc += Prm[row][e] * Vsm[e][dd];
        yxctx[((size_t)b * 1024 + c * 64 + row) * 512 + h * 64 + dd] = acc;
    }
}

// ---------------------------------------------------------------- LayerNorm
__global__ __launch_bounds__(256) void k_ln(
    const float* __restrict__ x, const float* __restrict__ residf,
    const void* __restrict__ residany, const void* __restrict__ gv,
    const void* __restrict__ bv, float* __restrict__ out32,
    void* __restrict__ outany, size_t ooff, const int* __restrict__ flagp) {
    int isbf = *flagp;
    int wave = threadIdx.x >> 6, lane = threadIdx.x & 63;
    int row = blockIdx.x * 4 + wave;
    const float* px = x + (size_t)row * 512;
    float v[8];
#pragma unroll
    for (int j = 0; j < 8; j++) {
        int col = lane + 64 * j;
        v[j] = px[col];
        if (residf) v[j] += residf[(size_t)row * 512 + col];
        if (residany) v[j] += ldany(residany, (size_t)row * 512 + col, isbf);
    }
    float sum = 0.f;
#pragma unroll
    for (int j = 0; j < 8; j++) sum += v[j];
#pragma unroll
    for (int off = 32; off >= 1; off >>= 1) sum += __shfl_xor(sum, off, 64);
    float mean = sum * (1.f / 512.f);
    float var = 0.f;
#pragma unroll
    for (int j = 0; j < 8; j++) {
        float d = v[j] - mean;
        var += d * d;
    }
#pragma unroll
    for (int off = 32; off >= 1; off >>= 1) var += __shfl_xor(var, off, 64);
    var *= (1.f / 512.f);
    float inv = rsqrtf(var + 1e-5f);
#pragma unroll
    for (int j = 0; j < 8; j++) {
        int col = lane + 64 * j;
        float y = (v[j] - mean) * inv * ldany(gv, col, isbf) +
                  ldany(bv, col, isbf);
        size_t oidx = (size_t)row * 512 + col;
        if (out32) out32[oidx] = y;
        if (outany) {
            if (isbf)
                ((bf16*)outany + ooff)[oidx] = __float2bfloat16(y);
            else
                ((float*)outany + ooff)[oidx] = y;
        }
    }
}

// ================================================================ launch
extern "C" void kernel_launch(void* const* d_in, const int* in_sizes, int n_in,
                              void* d_out, int out_size, void* d_ws,
                              size_t ws_size, hipStream_t stream) {
    (void)in_sizes; (void)n_in; (void)out_size; (void)ws_size;
    const void* dec_in = d_in[0];
    const void* p_in = d_in[1];
    const void* enc_in = d_in[2];

    const size_t M1 = 1048576;
    float* ws = (float*)d_ws;
    float* A_ = ws + 0 * M1;  // sa_q proj -> yx2
    float* B_ = ws + 1 * M1;  // sa_k -> pk_k -> ff1[0:1M]
    float* C_ = ws + 2 * M1;  // sa_v -> pk_v -> up_q ; ff1[1M:2M]
    float* D_ = ws + 3 * M1;  // sa_pc -> ca_lin out ; ff1[2M:3M]
    float* E_ = ws + 4 * M1;  // self-attn out -> mha2 ctx ; ff1[3M:4M]
    float* F_ = ws + 5 * M1;  // post-self-attn resid -> ff2
    float* S_ = ws + 6 * M1;  // scratch
    float* pattn = S_;                  // 512K (-> sbuf)
    float* L1 = S_ + 524288;            // 512K
    float* L2 = S_ + 1048576;           // 512K (-> part)
    float* pqp = S_ + 1572864;          // 32K
    float* pkq = S_ + 1605632;          // 32K
    float* ypraw = S_ + 1638400;        // 32K
    float* upk = S_ + 1671168;          // 32K
    float* upv = S_ + 1703936;          // 32K
    float* sbuf = S_;                   // alias pattn (dead after eca3)
    float* part = S_ + 1048576;         // alias L2 (dead after eca3)
    float* ff1 = B_;                    // 4M spanning B_..E_
    float* ff2 = F_;
    int* flagp = (int*)(S_ + 1736704);
    // bf16 transposed weights: 13 squares (512x512) + ff1t (2048x512) +
    // ff2t (512x2048). 5.5M shorts = 2.75M floats; total ws ~43.3 MB.
    short* wt = (short*)(S_ + 1769472);
    short* ff1t = wt + 13 * 262144;
    short* ff2t = ff1t + 1048576;
    auto WTp = [&](int wi) {
        return (const void*)(wt + (size_t)((wi - 6) / 2) * 262144);
    };

    hipStream_t S = stream;
    k_detect<<<1, 64, 0, S>>>(dec_in, flagp);
    {
        WT13 w13;
        for (int s = 0; s < 13; s++) w13.src[s] = d_in[6 + 2 * s];
        k_wtrans<<<dim3(16, 16, 13), 256, 0, S>>>(w13, wt, 512, 512, flagp);
        WT13 w1;
        w1.src[0] = d_in[38];
        k_wtrans<<<dim3(64, 16, 1), 256, 0, S>>>(w1, ff1t, 512, 2048, flagp);
        WT13 w2;
        w2.src[0] = d_in[40];
        k_wtrans<<<dim3(16, 64, 1), 256, 0, S>>>(w2, ff2t, 2048, 512, flagp);
    }

    auto Bv = [&](int i) { return (const void*)d_in[i]; };
    auto mf = [&](int aext, const void* A, GArgs g, const float* res,
                  const void* resany, int M, int Ncat, int Nper, int K,
                  int relu) {
        dim3 grid((unsigned)(Ncat / 64), (unsigned)(M / 64));
        if (aext)
            k_gemm_mfma<1><<<grid, 256, 0, S>>>(A, g, res, resany, Nper, K,
                                                relu, flagp);
        else
            k_gemm_mfma<0><<<grid, 256, 0, S>>>(A, g, res, resany, Nper, K,
                                                relu, flagp);
    };

    // --- self attention projections (fused: q, pc, k, v share A=dec) ---
    {
        GArgs g = {{WTp(6), WTp(10), WTp(12), WTp(14)},
                   {Bv(7), Bv(11), Bv(13), Bv(15)},
                   {0.125f, 1.f, 1.f, 1.f},
                   {A_, D_, B_, C_}};
        mf(1, dec_in, g, nullptr, nullptr, 2048, 2048, 512, 512, 0);
    }
    // --- p projections (fused: sa_pq + pk_q, both scaled) ---
    {
        GArgs g = {{WTp(8), WTp(18), WTp(8), WTp(8)},
                   {Bv(9), Bv(19), Bv(9), Bv(9)},
                   {0.125f, 0.125f, 0.f, 0.f},
                   {pqp, pkq, pqp, pqp}};
        mf(1, p_in, g, nullptr, nullptr, 64, 1024, 512, 512, 0);
    }
    k_pattn<<<dim3(128, 16), 256, 0, S>>>(D_, pqp, pattn);
    k_eca1<<<dim3(16, 16), 256, 0, S>>>(B_, C_, pattn, L1, L2);
    k_scan<<<128, 256, 0, S>>>(L1, L2);
    k_eca3<<<dim3(16, 16), 512, 0, S>>>(A_, B_, C_, pattn, L1, L2, E_);
    {  // sa_out + residual(dec)
        GArgs g = {{WTp(16), WTp(16), WTp(16), WTp(16)},
                   {Bv(17), Bv(17), Bv(17), Bv(17)},
                   {1.f, 1.f, 1.f, 1.f},
                   {F_, F_, F_, F_}};
        mf(0, E_, g, nullptr, dec_in, 2048, 512, 512, 512, 0);
    }

    // --- cross attention: Yp = MHA(p, enc, enc) ---
    {  // pk_k + pk_v fused (A=enc)
        GArgs g = {{WTp(20), WTp(22), WTp(20), WTp(20)},
                   {Bv(21), Bv(23), Bv(21), Bv(21)},
                   {1.f, 1.f, 1.f, 1.f},
                   {B_, C_, B_, B_}};
        mf(1, enc_in, g, nullptr, nullptr, 2048, 1024, 512, 512, 0);
    }
    k_mha1_scores<<<dim3(16, 16), 256, 0, S>>>(pkq, B_, sbuf);
    k_softmax_rows<<<512 / 4, 256, 0, S>>>(sbuf, 1024);
    k_mha1_ctx_p<<<dim3(16, 16), 256, 0, S>>>(sbuf, C_, part);
    k_mha1_ctx_r<<<128, 256, 0, S>>>(part, ypraw);

    // --- Yx = MHA(dec, Yp_raw, Yp_raw) ---
    {  // up_k + up_v fused (A=ypraw)
        GArgs g = {{WTp(26), WTp(28), WTp(26), WTp(26)},
                   {Bv(27), Bv(29), Bv(27), Bv(27)},
                   {1.f, 1.f, 1.f, 1.f},
                   {upk, upv, upk, upk}};
        mf(0, ypraw, g, nullptr, nullptr, 64, 1024, 512, 512, 0);
    }
    {  // up_q (scaled)
        GArgs g = {{WTp(24), WTp(24), WTp(24), WTp(24)},
                   {Bv(25), Bv(25), Bv(25), Bv(25)},
                   {0.125f, 0.125f, 0.125f, 0.125f},
                   {C_, C_, C_, C_}};
        mf(0, F_, g, nullptr, nullptr, 2048, 512, 512, 512, 0);
    }
    // Yp output = LN(Yp_raw + p)
    k_ln<<<64 / 4, 256, 0, S>>>(ypraw, nullptr, p_in, d_in[32], d_in[33],
                                nullptr, d_out, 1048576, flagp);
    k_mha2<<<dim3(16, 16), 256, 0, S>>>(C_, upk, upv, E_);
    {  // ca_lin
        GArgs g = {{WTp(30), WTp(30), WTp(30), WTp(30)},
                   {Bv(31), Bv(31), Bv(31), Bv(31)},
                   {1.f, 1.f, 1.f, 1.f},
                   {D_, D_, D_, D_}};
        mf(0, E_, g, nullptr, nullptr, 2048, 512, 512, 512, 0);
    }
    k_ln<<<2048 / 4, 256, 0, S>>>(D_, F_, nullptr, d_in[34], d_in[35], A_,
                                  nullptr, 0, flagp);  // yx2 -> A_

    // --- FFN ---
    {  // ff1 + relu
        GArgs g = {{ff1t, ff1t, ff1t, ff1t},
                   {Bv(39), Bv(39), Bv(39), Bv(39)},
                   {1.f, 1.f, 1.f, 1.f},
                   {ff1, ff1, ff1, ff1}};
        mf(0, A_, g, nullptr, nullptr, 2048, 2048, 2048, 512, 1);
    }
    {  // ff2
        GArgs g = {{ff2t, ff2t, ff2t, ff2t},
                   {Bv(41), Bv(41), Bv(41), Bv(41)},
                   {1.f, 1.f, 1.f, 1.f},
                   {ff2, ff2, ff2, ff2}};
        mf(0, ff1, g, nullptr, nullptr, 2048, 512, 512, 2048, 0);
    }
    k_ln<<<2048 / 4, 256, 0, S>>>(ff2, A_, nullptr, d_in[36], d_in[37],
                                  nullptr, d_out, 0, flagp);
}

// Round 9
// 512.954 us; speedup vs baseline: 1.0230x; 1.0230x over previous
//
#include <hip/hip_runtime.h>
#include <hip/hip_bf16.h>

typedef __hip_bfloat16 bf16;
typedef __attribute__((ext_vector_type(8))) short bf8_t;  // 8 bf16 (4 VGPR)
typedef __attribute__((ext_vector_type(4))) float f4_t;

__device__ __forceinline__ float b2f(bf16 x) { return __bfloat162float(x); }

__device__ __forceinline__ float ldany(const void* p, size_t i, int isbf) {
    return isbf ? b2f(((const bf16*)p)[i]) : ((const float*)p)[i];
}

// fp32 -> bf16 (RTN-even), bit pattern as short
__device__ __forceinline__ short f2b(float f) {
    unsigned u = __builtin_bit_cast(unsigned, f);
    u += 0x7fffu + ((u >> 16) & 1u);
    return (short)(u >> 16);
}

// ---------------------------------------------------------------- dtype detect
__global__ __launch_bounds__(64) void k_detect(const void* __restrict__ dec,
                                               int* __restrict__ flag) {
    __shared__ int cnt;
    if (threadIdx.x == 0) cnt = 0;
    __syncthreads();
    int bad = 0;
    for (int i = threadIdx.x; i < 256; i += 64) {
        float f = b2f(((const bf16*)dec)[i]);
        float a = fabsf(f);
        if (!(a < 1e10f) || (a != 0.f && a < 1e-20f)) bad++;
    }
    atomicAdd(&cnt, bad);
    __syncthreads();
    if (threadIdx.x == 0) *flag = (cnt >= 3) ? 0 : 1;  // 0=fp32, 1=bf16
}

// ---------------------------------------------------------------- to-bf16
__global__ __launch_bounds__(256) void k_tobf(const void* __restrict__ src,
                                              short* __restrict__ dst, int n,
                                              const int* __restrict__ flagp) {
    int isbf = *flagp;
    int i = blockIdx.x * 256 + threadIdx.x;
    if (i < n) dst[i] = isbf ? ((const short*)src)[i]
                             : f2b(((const float*)src)[i]);
}

// ---------------------------------------------------------------- weight prep
// W (K,N) -> Wt (N,K) bf16: 0.5 MB/slab (L2-resident), b128-readable.
struct WT13 {
    const void* src[13];
};

__global__ __launch_bounds__(256) void k_wtrans(WT13 w, short* __restrict__ dst,
                                                int K, int N,
                                                const int* __restrict__ flagp) {
    __shared__ float T[32][33];
    int isbf = *flagp;
    const void* src = w.src[blockIdx.z];
    short* d = dst + (size_t)blockIdx.z * K * N;
    int nb = blockIdx.x * 32, kb = blockIdx.y * 32;
    int col = threadIdx.x & 31, row0 = threadIdx.x >> 5;
#pragma unroll
    for (int i = 0; i < 4; i++) {
        int r = row0 + i * 8;
        T[r][col] = ldany(src, (size_t)(kb + r) * N + nb + col, isbf);
    }
    __syncthreads();
#pragma unroll
    for (int i = 0; i < 4; i++) {
        int r = row0 + i * 8;
        d[(size_t)(nb + r) * K + kb + col] = f2b(T[col][r]);
    }
}

// ---------------------------------------------------------------- MFMA GEMM
// All-bf16 operands: A (M,K) bf16, Wt (Nper,K) bf16. 64x64 tile, BK=64,
// 4 waves x (64m x 16n), acc=16 VGPR, 4x int4 loads in flight, no convert
// in the hot loop. Out (fp32) and OutBf (bf16 mirror) both optional.
struct GArgs {
    const short* W[4];
    const void* Bias[4];
    float scale[4];
    float* Out[4];
    short* OutBf[4];
};

__global__ __launch_bounds__(256, 4) void k_gemm_mfma(
    const short* __restrict__ A, GArgs g, const float* __restrict__ Res,
    const void* __restrict__ ResAny, int Nper, int K, int relu,
    const int* __restrict__ flagp) {
    constexpr int ASTR = 72;
    constexpr int BSTR = 72;
    __shared__ __align__(16) short As[64 * ASTR];
    __shared__ __align__(16) short Bs[64 * BSTR];
    int isbf = *flagp;
    int tid = threadIdx.x;
    int wave = tid >> 6, lane = tid & 63;
    int quad = lane >> 4, l16 = lane & 15;
    int mb = blockIdx.y * 64;
    int nbg = blockIdx.x * 64;
    int slot = nbg / Nper;
    int nb = nbg - slot * Nper;
    const short* Wt = g.W[slot];
    int wn = wave * 16;
    f4_t acc[4] = {};

    for (int k0 = 0; k0 < K; k0 += 64) {
        int4 av[2], bv[2];
#pragma unroll
        for (int i = 0; i < 2; i++) {
            int chunk = tid + 256 * i;  // 0..511
            int r = chunk >> 3, k8 = (chunk & 7) * 8;
            av[i] = *(const int4*)(A + (size_t)(mb + r) * K + k0 + k8);
            bv[i] = *(const int4*)(Wt + (size_t)(nb + r) * K + k0 + k8);
        }
        __syncthreads();  // previous iteration's frag reads done
#pragma unroll
        for (int i = 0; i < 2; i++) {
            int chunk = tid + 256 * i;
            int r = chunk >> 3, k8 = (chunk & 7) * 8;
            *(int4*)&As[r * ASTR + k8] = av[i];
            *(int4*)&Bs[r * BSTR + k8] = bv[i];
        }
        __syncthreads();
#pragma unroll
        for (int half = 0; half < 2; half++) {
            bf8_t b = *(const bf8_t*)&Bs[(wn + l16) * BSTR + half * 32 +
                                         quad * 8];
#pragma unroll
            for (int fi = 0; fi < 4; fi++) {
                bf8_t a = *(const bf8_t*)&As[(fi * 16 + l16) * ASTR +
                                             half * 32 + quad * 8];
                acc[fi] = __builtin_amdgcn_mfma_f32_16x16x32_bf16(a, b,
                                                                  acc[fi],
                                                                  0, 0, 0);
            }
        }
    }
    const void* Bias = g.Bias[slot];
    float scale = g.scale[slot];
    float* O = g.Out[slot];
    short* Ob = g.OutBf[slot];
    int n = nb + wn + l16;
    float bia = ldany(Bias, n, isbf);
#pragma unroll
    for (int fi = 0; fi < 4; fi++) {
#pragma unroll
        for (int r = 0; r < 4; r++) {
            int m = mb + fi * 16 + quad * 4 + r;
            float v = (acc[fi][r] + bia) * scale;
            if (relu) v = fmaxf(v, 0.f);
            if (Res) v += Res[(size_t)m * Nper + n];
            if (ResAny) v += ldany(ResAny, (size_t)m * Nper + n, isbf);
            if (O) O[(size_t)m * Nper + n] = v;
            if (Ob) Ob[(size_t)m * Nper + n] = f2b(v);
        }
    }
}

// ---------------------------------------------------------------- pattn
__global__ __launch_bounds__(256) void k_pattn(const float* __restrict__ pcp,
                                               const float* __restrict__ pqp,
                                               float* __restrict__ pattn) {
    __shared__ float pcs[8][65];
    __shared__ float pqs[32][65];
    int bh = blockIdx.y, tb = blockIdx.x;
    int b = bh >> 3, h = bh & 7;
    for (int lin = threadIdx.x; lin < 512; lin += 256) {
        int tt = lin >> 6, dd = lin & 63;
        pcs[tt][dd] = pcp[((size_t)b * 1024 + tb * 8 + tt) * 512 + h * 64 + dd];
    }
    for (int lin = threadIdx.x; lin < 2048; lin += 256) {
        int e = lin >> 6, dd = lin & 63;
        pqs[e][dd] = pqp[(size_t)(b * 32 + e) * 512 + h * 64 + dd];
    }
    __syncthreads();
    int e = threadIdx.x & 31, tt = threadIdx.x >> 5;
    float s = 0.f;
#pragma unroll
    for (int dd = 0; dd < 64; dd++) s += pcs[tt][dd] * pqs[e][dd];
    float r = (s > 0.f) ? (s + log2f(1.f + exp2f(-s))) : log2f(1.f + exp2f(s));
    pattn[((size_t)bh * 1024 + tb * 8 + tt) * 32 + e] = r;
}

// ---------------------------------------------------------------- ECA phase 1
__global__ __launch_bounds__(256) void k_eca1(
    const float* __restrict__ kp, const float* __restrict__ vp,
    const float* __restrict__ pattn, float* __restrict__ L1,
    float* __restrict__ L2) {
    __shared__ float Ks[64][65];
    __shared__ float Vs[64][65];
    __shared__ float Ps[64][33];
    int bh = blockIdx.y, c = blockIdx.x;
    int b = bh >> 3, h = bh & 7;
    size_t rowbase = (size_t)b * 1024 + c * 64;
    for (int ch = threadIdx.x; ch < 1024; ch += 256) {
        int s = ch >> 4, d4 = (ch & 15) * 4;
        size_t gidx = (rowbase + s) * 512 + h * 64 + d4;
        float4 k4 = *(const float4*)&kp[gidx];
        float4 v4 = *(const float4*)&vp[gidx];
        Ks[s][d4] = k4.x; Ks[s][d4 + 1] = k4.y;
        Ks[s][d4 + 2] = k4.z; Ks[s][d4 + 3] = k4.w;
        Vs[s][d4] = v4.x; Vs[s][d4 + 1] = v4.y;
        Vs[s][d4 + 2] = v4.z; Vs[s][d4 + 3] = v4.w;
    }
    for (int ch = threadIdx.x; ch < 512; ch += 256) {
        int s = ch >> 3, e4 = (ch & 7) * 4;
        float4 p4 = *(const float4*)&pattn[((size_t)bh * 1024 + c * 64 + s) * 32 + e4];
        Ps[s][e4] = p4.x; Ps[s][e4 + 1] = p4.y;
        Ps[s][e4 + 2] = p4.z; Ps[s][e4 + 3] = p4.w;
    }
    __syncthreads();
    size_t lbase = ((size_t)bh * 16 + c) * 2048;
    {
        int e = threadIdx.x & 31, dd0 = (threadIdx.x >> 5) * 8;
        float acc[8] = {};
        for (int s = 0; s < 64; s++) {
            float ps = Ps[s][e];
#pragma unroll
            for (int j = 0; j < 8; j++) acc[j] += Ks[s][dd0 + j] * ps;
        }
#pragma unroll
        for (int j = 0; j < 8; j++) L1[lbase + (dd0 + j) * 32 + e] = acc[j];
    }
    {
        int dd = threadIdx.x & 63, e0 = (threadIdx.x >> 6) * 8;
        float acc[8] = {};
        for (int s = 0; s < 64; s++) {
            float vv = Vs[s][dd];
#pragma unroll
            for (int j = 0; j < 8; j++) acc[j] += Ps[s][e0 + j] * vv;
        }
#pragma unroll
        for (int j = 0; j < 8; j++) L2[lbase + (e0 + j) * 64 + dd] = acc[j];
    }
}

// ---------------------------------------------------------------- chunk scan
__global__ __launch_bounds__(256) void k_scan(float* __restrict__ L1,
                                              float* __restrict__ L2) {
    int gid = blockIdx.x * 256 + threadIdx.x;  // 32768 = 16 bh * 2048
    int bh = gid >> 11, lin = gid & 2047;
    size_t base = (size_t)bh * 16 * 2048 + lin;
    float run = 0.f;
#pragma unroll
    for (int c = 0; c < 16; c++) {
        float v = L1[base + c * 2048];
        L1[base + c * 2048] = run;
        run += v;
    }
    run = 0.f;
#pragma unroll
    for (int c = 0; c < 16; c++) {
        float v = L2[base + c * 2048];
        L2[base + c * 2048] = run;
        run += v;
    }
}

// ---------------------------------------------------------------- ECA phase 3
// Output attn written as bf16 only (sole consumer is the sa_out GEMM).
__global__ __launch_bounds__(512) void k_eca3(
    const float* __restrict__ qp, const float* __restrict__ kp,
    const float* __restrict__ vp, const float* __restrict__ pattn,
    const float* __restrict__ L1s, const float* __restrict__ L2s,
    short* __restrict__ attnbf) {
    __shared__ float R0[64][65];
    __shared__ float R1[64][65];
    __shared__ float Ps[64][33];
    __shared__ float SS[2112];
    __shared__ float Pr[64][33];
    int bh = blockIdx.y, c = blockIdx.x;
    int b = bh >> 3, h = bh & 7;
    size_t rowbase = (size_t)b * 1024 + c * 64;
    int tid = threadIdx.x;
    for (int ch = tid; ch < 1024; ch += 512) {
        int t = ch >> 4, d4 = (ch & 15) * 4;
        size_t gidx = (rowbase + t) * 512 + h * 64 + d4;
        float4 q4 = *(const float4*)&qp[gidx];
        float4 k4 = *(const float4*)&kp[gidx];
        R0[t][d4] = q4.x; R0[t][d4 + 1] = q4.y;
        R0[t][d4 + 2] = q4.z; R0[t][d4 + 3] = q4.w;
        R1[t][d4] = k4.x; R1[t][d4 + 1] = k4.y;
        R1[t][d4 + 2] = k4.z; R1[t][d4 + 3] = k4.w;
    }
    if (tid < 512) {
        int ch = tid;
        {
            int t = ch >> 3, e4 = (ch & 7) * 4;
            float4 p4 = *(const float4*)&pattn[((size_t)bh * 1024 + c * 64 + t) * 32 + e4];
            Ps[t][e4] = p4.x; Ps[t][e4 + 1] = p4.y;
            Ps[t][e4 + 2] = p4.z; Ps[t][e4 + 3] = p4.w;
        }
        {
            float4 s4 = *(const float4*)&L1s[((size_t)bh * 16 + c) * 2048 + ch * 4];
            int dd = ch >> 3, e4 = (ch & 7) * 4;
            SS[dd * 33 + e4] = s4.x; SS[dd * 33 + e4 + 1] = s4.y;
            SS[dd * 33 + e4 + 2] = s4.z; SS[dd * 33 + e4 + 3] = s4.w;
        }
    }
    __syncthreads();
    int tx = tid & 15, ty = tid >> 4;
    float a1r[2][4] = {};
    float qs1[2][2] = {};
    for (int dd = 0; dd < 64; dd++) {
        float q2[2], k4[4];
#pragma unroll
        for (int i = 0; i < 2; i++) q2[i] = R0[ty * 2 + i][dd];
#pragma unroll
        for (int j = 0; j < 4; j++) k4[j] = R1[tx * 4 + j][dd];
#pragma unroll
        for (int i = 0; i < 2; i++)
#pragma unroll
            for (int j = 0; j < 4; j++) a1r[i][j] += q2[i] * k4[j];
        float s1a = SS[dd * 33 + tx * 2], s1b = SS[dd * 33 + tx * 2 + 1];
#pragma unroll
        for (int i = 0; i < 2; i++) {
            qs1[i][0] += q2[i] * s1a;
            qs1[i][1] += q2[i] * s1b;
        }
    }
    __syncthreads();
#pragma unroll
    for (int i = 0; i < 2; i++) {
#pragma unroll
        for (int j = 0; j < 4; j++) R0[ty * 2 + i][tx * 4 + j] = a1r[i][j];
        Pr[ty * 2 + i][tx * 2] = qs1[i][0];
        Pr[ty * 2 + i][tx * 2 + 1] = qs1[i][1];
    }
    for (int ch = tid; ch < 1024; ch += 512) {
        int t = ch >> 4, d4 = (ch & 15) * 4;
        float4 v4 = *(const float4*)&vp[(rowbase + t) * 512 + h * 64 + d4];
        R1[t][d4] = v4.x; R1[t][d4 + 1] = v4.y;
        R1[t][d4 + 2] = v4.z; R1[t][d4 + 3] = v4.w;
    }
    __syncthreads();
    {
        int e = tid & 31, t0 = (tid >> 5) * 4;
        for (int k2 = 0; k2 < 4; k2++) {
            int t = t0 + k2;
            float s = Pr[t][e];
            for (int s2 = 0; s2 <= t; s2++) s += R0[t][s2] * Ps[s2][e];
            Pr[t][e] = s / (float)(c * 64 + t + 1);
        }
    }
    __syncthreads();
    if (tid < 64) {
        float m = -1e30f;
        for (int e = 0; e < 32; e++) m = fmaxf(m, Pr[tid][e]);
        float sum = 0.f;
        for (int e = 0; e < 32; e++) {
            float ex = expf(Pr[tid][e] - m);
            Pr[tid][e] = ex;
            sum += ex;
        }
        float inv = 1.f / sum;
        for (int e = 0; e < 32; e++) Pr[tid][e] *= inv;
    } else if (tid >= 128) {
        for (int ch = tid - 128; ch < 512; ch += 384) {
            float4 s4 = *(const float4*)&L2s[((size_t)bh * 16 + c) * 2048 + ch * 4];
            int e = ch >> 4, d4 = (ch & 15) * 4;
            SS[e * 65 + d4] = s4.x; SS[e * 65 + d4 + 1] = s4.y;
            SS[e * 65 + d4 + 2] = s4.z; SS[e * 65 + d4 + 3] = s4.w;
        }
    }
    __syncthreads();
    float a2r[2][4] = {};
    float ps2[2][4] = {};
    for (int e = 0; e < 32; e++) {
        float p2[2], b4[4], v4[4];
#pragma unroll
        for (int i = 0; i < 2; i++) p2[i] = Pr[ty * 2 + i][e];
#pragma unroll
        for (int j = 0; j < 4; j++) {
            b4[j] = Ps[tx * 4 + j][e];
            v4[j] = SS[e * 65 + tx * 4 + j];
        }
#pragma unroll
        for (int i = 0; i < 2; i++)
#pragma unroll
            for (int j = 0; j < 4; j++) {
                a2r[i][j] += p2[i] * b4[j];
                ps2[i][j] += p2[i] * v4[j];
            }
    }
    __syncthreads();
#pragma unroll
    for (int i = 0; i < 2; i++)
#pragma unroll
        for (int j = 0; j < 4; j++) R0[ty * 2 + i][tx * 4 + j] = a2r[i][j];
    __syncthreads();
#pragma unroll
    for (int i = 0; i < 2; i++) {
        int t = ty * 2 + i;
        float acch[4];
#pragma unroll
        for (int j = 0; j < 4; j++) acch[j] = ps2[i][j];
        for (int s = 0; s <= t; s++) {
            float a2v = R0[t][s];
#pragma unroll
            for (int j = 0; j < 4; j++) acch[j] += a2v * R1[s][tx * 4 + j];
        }
        float inv = 1.f / (float)(c * 64 + t + 1);
        short4 o;
        o.x = f2b(acch[0] * inv); o.y = f2b(acch[1] * inv);
        o.z = f2b(acch[2] * inv); o.w = f2b(acch[3] * inv);
        *(short4*)&attnbf[(rowbase + t) * 512 + h * 64 + tx * 4] = o;
    }
}

// ---------------------------------------------------------------- MHA1 scores
__global__ __launch_bounds__(256) void k_mha1_scores(
    const float* __restrict__ pkq, const float* __restrict__ pkk,
    float* __restrict__ sbuf) {
    __shared__ float Qs[32][65];
    __shared__ float Ks[64][65];
    int bh = blockIdx.y, kb = blockIdx.x;
    int b = bh >> 3, h = bh & 7;
    for (int lin = threadIdx.x; lin < 2048; lin += 256) {
        int i = lin >> 6, dd = lin & 63;
        Qs[i][dd] = pkq[(size_t)(b * 32 + i) * 512 + h * 64 + dd];
    }
    for (int lin = threadIdx.x; lin < 4096; lin += 256) {
        int kk = lin >> 6, dd = lin & 63;
        Ks[kk][dd] = pkk[((size_t)b * 1024 + kb * 64 + kk) * 512 + h * 64 + dd];
    }
    __syncthreads();
    int kk = threadIdx.x & 63, i0 = (threadIdx.x >> 6) * 8;
    for (int ii = 0; ii < 8; ii++) {
        int i = i0 + ii;
        float s = 0.f;
#pragma unroll
        for (int dd = 0; dd < 64; dd++) s += Qs[i][dd] * Ks[kk][dd];
        sbuf[((size_t)bh * 32 + i) * 1024 + kb * 64 + kk] = s;
    }
}

// ---------------------------------------------------------------- row softmax
__global__ __launch_bounds__(256) void k_softmax_rows(float* __restrict__ buf,
                                                      int cols) {
    int wave = threadIdx.x >> 6, lane = threadIdx.x & 63;
    int row = blockIdx.x * 4 + wave;
    float* p = buf + (size_t)row * cols;
    int per = cols >> 6;
    float m = -1e30f;
    for (int j = 0; j < per; j++) m = fmaxf(m, p[lane + 64 * j]);
#pragma unroll
    for (int off = 32; off >= 1; off >>= 1) m = fmaxf(m, __shfl_xor(m, off, 64));
    float sum = 0.f;
    for (int j = 0; j < per; j++) {
        float ex = expf(p[lane + 64 * j] - m);
        p[lane + 64 * j] = ex;
        sum += ex;
    }
#pragma unroll
    for (int off = 32; off >= 1; off >>= 1) sum += __shfl_xor(sum, off, 64);
    float inv = 1.f / sum;
    for (int j = 0; j < per; j++) p[lane + 64 * j] *= inv;
}

// ---------------------------------------------------------------- MHA1 ctx
__global__ __launch_bounds__(256) void k_mha1_ctx_p(
    const float* __restrict__ sbuf, const float* __restrict__ pkv,
    float* __restrict__ part) {
    __shared__ float Vs[64][65];
    __shared__ float Ps[32][33];
    int bh = blockIdx.y, c = blockIdx.x;
    int b = bh >> 3, h = bh & 7;
    for (int lin = threadIdx.x; lin < 4096; lin += 256) {
        int kk = lin >> 6, dd = lin & 63;
        Vs[kk][dd] = pkv[((size_t)b * 1024 + c * 64 + kk) * 512 + h * 64 + dd];
    }
    for (int lin = threadIdx.x; lin < 2048; lin += 256) {
        int i = lin >> 6, kk = lin & 63;
        Ps[i][kk] = sbuf[((size_t)bh * 32 + i) * 1024 + c * 64 + kk];
    }
    __syncthreads();
    int dd = threadIdx.x & 63, ig = threadIdx.x >> 6;
    float acc[8] = {};
    for (int kk = 0; kk < 64; kk++) {
        float vv = Vs[kk][dd];
#pragma unroll
        for (int j = 0; j < 8; j++) acc[j] += Ps[ig * 8 + j][kk] * vv;
    }
    size_t base = ((size_t)bh * 16 + c) * 2048;
#pragma unroll
    for (int j = 0; j < 8; j++) part[base + (ig * 8 + j) * 64 + dd] = acc[j];
}

__global__ __launch_bounds__(256) void k_mha1_ctx_r(
    const float* __restrict__ part, float* __restrict__ yp_raw,
    short* __restrict__ yp_bf) {
    int gid = blockIdx.x * 256 + threadIdx.x;
    int bh = gid >> 11, rem = gid & 2047;
    int i = rem >> 6, dd = rem & 63;
    float s = 0.f;
#pragma unroll
    for (int c = 0; c < 16; c++) s += part[((size_t)bh * 16 + c) * 2048 + rem];
    int b = bh >> 3, h = bh & 7;
    size_t o = (size_t)(b * 32 + i) * 512 + h * 64 + dd;
    yp_raw[o] = s;
    yp_bf[o] = f2b(s);
}

// ---------------------------------------------------------------- MHA2 (fused)
// Output written as bf16 only (sole consumer is the ca_lin GEMM).
__global__ __launch_bounds__(256) void k_mha2(const float* __restrict__ upq,
                                              const float* __restrict__ upk,
                                              const float* __restrict__ upv,
                                              short* __restrict__ yxbf) {
    __shared__ float Ksm[32][65];
    __shared__ float Vsm[32][65];
    __shared__ float Qsm[64][65];
    __shared__ float Prm[64][33];
    int bh = blockIdx.y, c = blockIdx.x;
    int b = bh >> 3, h = bh & 7;
    for (int lin = threadIdx.x; lin < 2048; lin += 256) {
        int e = lin >> 6, dd = lin & 63;
        Ksm[e][dd] = upk[(size_t)(b * 32 + e) * 512 + h * 64 + dd];
        Vsm[e][dd] = upv[(size_t)(b * 32 + e) * 512 + h * 64 + dd];
    }
    for (int lin = threadIdx.x; lin < 4096; lin += 256) {
        int t = lin >> 6, dd = lin & 63;
        Qsm[t][dd] = upq[((size_t)b * 1024 + c * 64 + t) * 512 + h * 64 + dd];
    }
    __syncthreads();
    int row = threadIdx.x >> 2, r = threadIdx.x & 3;
    float p[8];
#pragma unroll
    for (int j = 0; j < 8; j++) {
        int e = r * 8 + j;
        float s = 0.f;
#pragma unroll
        for (int dd = 0; dd < 64; dd++) s += Qsm[row][dd] * Ksm[e][dd];
        p[j] = s;
    }
    float m = -1e30f;
#pragma unroll
    for (int j = 0; j < 8; j++) m = fmaxf(m, p[j]);
    m = fmaxf(m, __shfl_xor(m, 1, 64));
    m = fmaxf(m, __shfl_xor(m, 2, 64));
    float sum = 0.f;
#pragma unroll
    for (int j = 0; j < 8; j++) {
        p[j] = expf(p[j] - m);
        sum += p[j];
    }
    sum += __shfl_xor(sum, 1, 64);
    sum += __shfl_xor(sum, 2, 64);
    float inv = 1.f / sum;
#pragma unroll
    for (int j = 0; j < 8; j++) Prm[row][r * 8 + j] = p[j] * inv;
    __syncthreads();
    for (int j4 = 0; j4 < 4; j4++) {
        short4 o;
        float a4[4];
#pragma unroll
        for (int q = 0; q < 4; q++) {
            int dd = r * 16 + j4 * 4 + q;
            float acc = 0.f;
#pragma unroll
            for (int e = 0; e < 32; e++) acc += Prm[row][e] * Vsm[e][dd];
            a4[q] = acc;
        }
        o.x = f2b(a4[0]); o.y = f2b(a4[1]);
        o.z = f2b(a4[2]); o.w = f2b(a4[3]);
        *(short4*)&yxbf[((size_t)b * 1024 + c * 64 + row) * 512 + h * 64 +
                        r * 16 + j4 * 4] = o;
    }
}

// ---------------------------------------------------------------- LayerNorm
__global__ __launch_bounds__(256) void k_ln(
    const float* __restrict__ x, const float* __restrict__ residf,
    const void* __restrict__ residany, const void* __restrict__ gv,
    const void* __restrict__ bv, float* __restrict__ out32,
    short* __restrict__ dupbf, void* __restrict__ outany, size_t ooff,
    const int* __restrict__ flagp) {
    int isbf = *flagp;
    int wave = threadIdx.x >> 6, lane = threadIdx.x & 63;
    int row = blockIdx.x * 4 + wave;
    const float* px = x + (size_t)row * 512;
    float v[8];
#pragma unroll
    for (int j = 0; j < 8; j++) {
        int col = lane + 64 * j;
        v[j] = px[col];
        if (residf) v[j] += residf[(size_t)row * 512 + col];
        if (residany) v[j] += ldany(residany, (size_t)row * 512 + col, isbf);
    }
    float sum = 0.f;
#pragma unroll
    for (int j = 0; j < 8; j++) sum += v[j];
#pragma unroll
    for (int off = 32; off >= 1; off >>= 1) sum += __shfl_xor(sum, off, 64);
    float mean = sum * (1.f / 512.f);
    float var = 0.f;
#pragma unroll
    for (int j = 0; j < 8; j++) {
        float d = v[j] - mean;
        var += d * d;
    }
#pragma unroll
    for (int off = 32; off >= 1; off >>= 1) var += __shfl_xor(var, off, 64);
    var *= (1.f / 512.f);
    float inv = rsqrtf(var + 1e-5f);
#pragma unroll
    for (int j = 0; j < 8; j++) {
        int col = lane + 64 * j;
        float y = (v[j] - mean) * inv * ldany(gv, col, isbf) +
                  ldany(bv, col, isbf);
        size_t oidx = (size_t)row * 512 + col;
        if (out32) out32[oidx] = y;
        if (dupbf) dupbf[oidx] = f2b(y);
        if (outany) {
            if (isbf)
                ((bf16*)outany + ooff)[oidx] = __float2bfloat16(y);
            else
                ((float*)outany + ooff)[oidx] = y;
        }
    }
}

// ================================================================ launch
extern "C" void kernel_launch(void* const* d_in, const int* in_sizes, int n_in,
                              void* d_out, int out_size, void* d_ws,
                              size_t ws_size, hipStream_t stream) {
    (void)in_sizes; (void)n_in; (void)out_size; (void)ws_size;
    const void* dec_in = d_in[0];
    const void* p_in = d_in[1];
    const void* enc_in = d_in[2];

    const size_t M1 = 1048576;
    float* ws = (float*)d_ws;
    float* A_ = ws + 0 * M1;  // sa_q proj (fp32) -> yx2 fp32 (final resid)
    float* B_ = ws + 1 * M1;  // sa_k -> pk_k ; B_..C_ -> ff1_bf (4M shorts)
    float* C_ = ws + 2 * M1;  // sa_v -> pk_v -> up_q (fp32, mha2 reads)
    float* D_ = ws + 3 * M1;  // sa_pc -> ca_lin out (fp32, k_ln x)
    float* E_ = ws + 4 * M1;  // bf16 zone: attn_bf / mha2ctx_bf
    float* F_ = ws + 5 * M1;  // sa_out+resid fp32 -> ff2 out fp32
    float* S_ = ws + 6 * M1;  // scratch
    float* pattn = S_;                  // 512K (-> sbuf)
    float* L1 = S_ + 524288;            // 512K
    float* L2 = S_ + 1048576;           // 512K (-> part)
    float* pqp = S_ + 1572864;          // 32K
    float* pkq = S_ + 1605632;          // 32K
    float* ypraw = S_ + 1638400;        // 32K
    float* upk = S_ + 1671168;          // 32K
    float* upv = S_ + 1703936;          // 32K
    float* sbuf = S_;                   // alias pattn (dead after eca3)
    float* part = S_ + 1048576;         // alias L2 (dead after scan+eca3)
    int* flagp = (int*)(S_ + 1736704);
    // bf16 buffers (shorts)
    short* attn_bf = (short*)E_;                  // 1M sh
    short* mha2_bf = (short*)(E_ + 524288);       // 1M sh
    short* ff1_bf = (short*)B_;                   // 4M sh spanning B_..C_
    short* dec_bf = (short*)(ws + 7 * M1 + 786432);   // 1M sh
    short* enc_bf = dec_bf + M1;                  // 1M sh
    short* p_bf = enc_bf + M1;                    // 32K sh
    short* F_bf = p_bf + 32768;                   // 1M sh
    short* yp_bf = F_bf + M1;                     // 32K sh
    short* yx2_bf = yp_bf + 32768;                // 1M sh
    short* wt = yx2_bf + M1;                      // 13*256K sh
    short* ff1t = wt + 13 * 262144;               // 1M sh
    short* ff2t = ff1t + M1;                      // 1M sh  (total ~50 MB)
    auto WTp = [&](int wi) { return wt + (size_t)((wi - 6) / 2) * 262144; };

    hipStream_t S = stream;
    k_detect<<<1, 64, 0, S>>>(dec_in, flagp);
    k_tobf<<<4096, 256, 0, S>>>(dec_in, dec_bf, 1048576, flagp);
    k_tobf<<<4096, 256, 0, S>>>(enc_in, enc_bf, 1048576, flagp);
    k_tobf<<<128, 256, 0, S>>>(p_in, p_bf, 32768, flagp);
    {
        WT13 w13;
        for (int s = 0; s < 13; s++) w13.src[s] = d_in[6 + 2 * s];
        k_wtrans<<<dim3(16, 16, 13), 256, 0, S>>>(w13, wt, 512, 512, flagp);
        WT13 w1;
        w1.src[0] = d_in[38];
        k_wtrans<<<dim3(64, 16, 1), 256, 0, S>>>(w1, ff1t, 512, 2048, flagp);
        WT13 w2;
        w2.src[0] = d_in[40];
        k_wtrans<<<dim3(16, 64, 1), 256, 0, S>>>(w2, ff2t, 2048, 512, flagp);
    }

    auto Bv = [&](int i) { return (const void*)d_in[i]; };
    auto mf = [&](const short* A, GArgs g, const float* res,
                  const void* resany, int M, int Ncat, int Nper, int K,
                  int relu) {
        dim3 grid((unsigned)(Ncat / 64), (unsigned)(M / 64));
        k_gemm_mfma<<<grid, 256, 0, S>>>(A, g, res, resany, Nper, K, relu,
                                         flagp);
    };
    short* nb16 = nullptr;
    float* nf32 = nullptr;

    // --- self attention projections (fused: q, pc, k, v share A=dec) ---
    {
        GArgs g = {{WTp(6), WTp(10), WTp(12), WTp(14)},
                   {Bv(7), Bv(11), Bv(13), Bv(15)},
                   {0.125f, 1.f, 1.f, 1.f},
                   {A_, D_, B_, C_},
                   {nb16, nb16, nb16, nb16}};
        mf(dec_bf, g, nullptr, nullptr, 2048, 2048, 512, 512, 0);
    }
    // --- p projections (fused: sa_pq + pk_q) ---
    {
        GArgs g = {{WTp(8), WTp(18), WTp(8), WTp(8)},
                   {Bv(9), Bv(19), Bv(9), Bv(9)},
                   {0.125f, 0.125f, 0.f, 0.f},
                   {pqp, pkq, pqp, pqp},
                   {nb16, nb16, nb16, nb16}};
        mf(p_bf, g, nullptr, nullptr, 64, 1024, 512, 512, 0);
    }
    k_pattn<<<dim3(128, 16), 256, 0, S>>>(D_, pqp, pattn);
    k_eca1<<<dim3(16, 16), 256, 0, S>>>(B_, C_, pattn, L1, L2);
    k_scan<<<128, 256, 0, S>>>(L1, L2);
    k_eca3<<<dim3(16, 16), 512, 0, S>>>(A_, B_, C_, pattn, L1, L2, attn_bf);
    {  // sa_out + residual(dec): fp32 F_ (LN resid) + bf16 F_bf (up_q A)
        GArgs g = {{WTp(16), WTp(16), WTp(16), WTp(16)},
                   {Bv(17), Bv(17), Bv(17), Bv(17)},
                   {1.f, 1.f, 1.f, 1.f},
                   {F_, F_, F_, F_},
                   {F_bf, F_bf, F_bf, F_bf}};
        mf(attn_bf, g, nullptr, dec_in, 2048, 512, 512, 512, 0);
    }

    // --- cross attention: Yp = MHA(p, enc, enc) ---
    {  // pk_k + pk_v fused (A=enc)
        GArgs g = {{WTp(20), WTp(22), WTp(20), WTp(20)},
                   {Bv(21), Bv(23), Bv(21), Bv(21)},
                   {1.f, 1.f, 1.f, 1.f},
                   {B_, C_, B_, B_},
                   {nb16, nb16, nb16, nb16}};
        mf(enc_bf, g, nullptr, nullptr, 2048, 1024, 512, 512, 0);
    }
    k_mha1_scores<<<dim3(16, 16), 256, 0, S>>>(pkq, B_, sbuf);
    k_softmax_rows<<<512 / 4, 256, 0, S>>>(sbuf, 1024);
    k_mha1_ctx_p<<<dim3(16, 16), 256, 0, S>>>(sbuf, C_, part);
    k_mha1_ctx_r<<<128, 256, 0, S>>>(part, ypraw, yp_bf);

    // --- Yx = MHA(dec, Yp_raw, Yp_raw) ---
    {  // up_k + up_v fused (A=ypraw)
        GArgs g = {{WTp(26), WTp(28), WTp(26), WTp(26)},
                   {Bv(27), Bv(29), Bv(27), Bv(27)},
                   {1.f, 1.f, 1.f, 1.f},
                   {upk, upv, upk, upk},
                   {nb16, nb16, nb16, nb16}};
        mf(yp_bf, g, nullptr, nullptr, 64, 1024, 512, 512, 0);
    }
    {  // up_q (scaled)
        GArgs g = {{WTp(24), WTp(24), WTp(24), WTp(24)},
                   {Bv(25), Bv(25), Bv(25), Bv(25)},
                   {0.125f, 0.125f, 0.125f, 0.125f},
                   {C_, C_, C_, C_},
                   {nb16, nb16, nb16, nb16}};
        mf(F_bf, g, nullptr, nullptr, 2048, 512, 512, 512, 0);
    }
    // Yp output = LN(Yp_raw + p)
    k_ln<<<64 / 4, 256, 0, S>>>(ypraw, nullptr, p_in, d_in[32], d_in[33],
                                nullptr, nullptr, d_out, 1048576, flagp);
    k_mha2<<<dim3(16, 16), 256, 0, S>>>(C_, upk, upv, mha2_bf);
    {  // ca_lin
        GArgs g = {{WTp(30), WTp(30), WTp(30), WTp(30)},
                   {Bv(31), Bv(31), Bv(31), Bv(31)},
                   {1.f, 1.f, 1.f, 1.f},
                   {D_, D_, D_, D_},
                   {nb16, nb16, nb16, nb16}};
        mf(mha2_bf, g, nullptr, nullptr, 2048, 512, 512, 512, 0);
    }
    k_ln<<<2048 / 4, 256, 0, S>>>(D_, F_, nullptr, d_in[34], d_in[35], A_,
                                  yx2_bf, nullptr, 0, flagp);  // yx2

    // --- FFN ---
    {  // ff1 + relu -> bf16 only (sole consumer is ff2 GEMM)
        GArgs g = {{ff1t, ff1t, ff1t, ff1t},
                   {Bv(39), Bv(39), Bv(39), Bv(39)},
                   {1.f, 1.f, 1.f, 1.f},
                   {nf32, nf32, nf32, nf32},
                   {ff1_bf, ff1_bf, ff1_bf, ff1_bf}};
        mf(yx2_bf, g, nullptr, nullptr, 2048, 2048, 2048, 512, 1);
    }
    {  // ff2
        GArgs g = {{ff2t, ff2t, ff2t, ff2t},
                   {Bv(41), Bv(41), Bv(41), Bv(41)},
                   {1.f, 1.f, 1.f, 1.f},
                   {F_, F_, F_, F_},
                   {nb16, nb16, nb16, nb16}};
        mf(ff1_bf, g, nullptr, nullptr, 2048, 512, 512, 2048, 0);
    }
    k_ln<<<2048 / 4, 256, 0, S>>>(F_, A_, nullptr, d_in[36], d_in[37],
                                  nullptr, nullptr, d_out, 0, flagp);
}

// Round 10
// 372.337 us; speedup vs baseline: 1.4093x; 1.3777x over previous
//
#include <hip/hip_runtime.h>
#include <hip/hip_bf16.h>

typedef __hip_bfloat16 bf16;
typedef __attribute__((ext_vector_type(8))) short bf8_t;  // 8 bf16 (4 VGPR)
typedef __attribute__((ext_vector_type(4))) float f4_t;

__device__ __forceinline__ float b2f(bf16 x) { return __bfloat162float(x); }

__device__ __forceinline__ float ldany(const void* p, size_t i, int isbf) {
    return isbf ? b2f(((const bf16*)p)[i]) : ((const float*)p)[i];
}

// fp32 -> bf16 (RTN-even), bit pattern as short
__device__ __forceinline__ short f2b(float f) {
    unsigned u = __builtin_bit_cast(unsigned, f);
    u += 0x7fffu + ((u >> 16) & 1u);
    return (short)(u >> 16);
}

// ---------------------------------------------------------------- dtype detect
__global__ __launch_bounds__(64) void k_detect(const void* __restrict__ dec,
                                               int* __restrict__ flag) {
    __shared__ int cnt;
    if (threadIdx.x == 0) cnt = 0;
    __syncthreads();
    int bad = 0;
    for (int i = threadIdx.x; i < 256; i += 64) {
        float f = b2f(((const bf16*)dec)[i]);
        float a = fabsf(f);
        if (!(a < 1e10f) || (a != 0.f && a < 1e-20f)) bad++;
    }
    atomicAdd(&cnt, bad);
    __syncthreads();
    if (threadIdx.x == 0) *flag = (cnt >= 3) ? 0 : 1;  // 0=fp32, 1=bf16
}

// ---------------------------------------------------------------- to-bf16
__global__ __launch_bounds__(256) void k_tobf(const void* __restrict__ src,
                                              short* __restrict__ dst, int n,
                                              const int* __restrict__ flagp) {
    int isbf = *flagp;
    int i = blockIdx.x * 256 + threadIdx.x;
    if (i < n) dst[i] = isbf ? ((const short*)src)[i]
                             : f2b(((const float*)src)[i]);
}

// ---------------------------------------------------------------- weight prep
struct WT13 {
    const void* src[13];
};

__global__ __launch_bounds__(256) void k_wtrans(WT13 w, short* __restrict__ dst,
                                                int K, int N,
                                                const int* __restrict__ flagp) {
    __shared__ float T[32][33];
    int isbf = *flagp;
    const void* src = w.src[blockIdx.z];
    short* d = dst + (size_t)blockIdx.z * K * N;
    int nb = blockIdx.x * 32, kb = blockIdx.y * 32;
    int col = threadIdx.x & 31, row0 = threadIdx.x >> 5;
#pragma unroll
    for (int i = 0; i < 4; i++) {
        int r = row0 + i * 8;
        T[r][col] = ldany(src, (size_t)(kb + r) * N + nb + col, isbf);
    }
    __syncthreads();
#pragma unroll
    for (int i = 0; i < 4; i++) {
        int r = row0 + i * 8;
        d[(size_t)(nb + r) * K + kb + col] = f2b(T[col][r]);
    }
}

// ---------------------------------------------------------------- MFMA GEMM
// All-bf16, 64x64 tile, BK=64. Software-pipelined K-loop: iteration k stores
// regs->LDS, ISSUES k+1's loads, then MFMAs -> the vmcnt wait for a load
// lands a full iteration later (R9's structure exposed a full memory
// round-trip every iteration: MfmaUtil 2.7%, all pipes idle). XCD swizzle
// gives each XCD a contiguous m-band so A-band+W fit its 4MiB L2.
struct GArgs {
    const short* W[4];
    const void* Bias[4];
    float scale[4];
    float* Out[4];
    short* OutBf[4];
};

__global__ __launch_bounds__(256, 6) void k_gemm_mfma(
    const short* __restrict__ A, GArgs g, const float* __restrict__ Res,
    const void* __restrict__ ResAny, int Nper, int K, int relu,
    const int* __restrict__ flagp) {
    constexpr int ASTR = 72;
    constexpr int BSTR = 72;
    __shared__ __align__(16) short As[64 * ASTR];
    __shared__ __align__(16) short Bs[64 * BSTR];
    int isbf = *flagp;
    int tid = threadIdx.x;
    int wave = tid >> 6, lane = tid & 63;
    int quad = lane >> 4, l16 = lane & 15;
    // XCD-aware remap: id&7 selects the XCD (round-robin dispatch); give each
    // a contiguous band of m-rows so its L2 holds the A-band + W slab.
    int gx = gridDim.x;
    int nblk = gx * gridDim.y;
    int id = blockIdx.y * gx + blockIdx.x;
    int bx = blockIdx.x, by = blockIdx.y;
    if ((nblk & 7) == 0) {
        int per = nblk >> 3;
        int id2 = (id & 7) * per + (id >> 3);
        by = id2 / gx;
        bx = id2 - by * gx;
    }
    int mb = by * 64;
    int nbg = bx * 64;
    int slot = nbg / Nper;
    int nb = nbg - slot * Nper;
    const short* Wt = g.W[slot];
    int wn = wave * 16;
    f4_t acc[4] = {};

    int ar = tid >> 3;          // 0..31
    int ak = (tid & 7) * 8;
    const short* Ap = A + (size_t)mb * K;
    const short* Wp = Wt + (size_t)nb * K;
    // prologue loads (k0 = 0)
    int4 av0 = *(const int4*)(Ap + (size_t)ar * K + ak);
    int4 av1 = *(const int4*)(Ap + (size_t)(ar + 32) * K + ak);
    int4 bv0 = *(const int4*)(Wp + (size_t)ar * K + ak);
    int4 bv1 = *(const int4*)(Wp + (size_t)(ar + 32) * K + ak);
    for (int k0 = 0; k0 < K; k0 += 64) {
        __syncthreads();  // previous iteration's MFMA reads done
        *(int4*)&As[ar * ASTR + ak] = av0;
        *(int4*)&As[(ar + 32) * ASTR + ak] = av1;
        *(int4*)&Bs[ar * BSTR + ak] = bv0;
        *(int4*)&Bs[(ar + 32) * BSTR + ak] = bv1;
        int kn = k0 + 64;
        if (kn < K) {  // prefetch next K-tile; waited on at NEXT store
            av0 = *(const int4*)(Ap + (size_t)ar * K + kn + ak);
            av1 = *(const int4*)(Ap + (size_t)(ar + 32) * K + kn + ak);
            bv0 = *(const int4*)(Wp + (size_t)ar * K + kn + ak);
            bv1 = *(const int4*)(Wp + (size_t)(ar + 32) * K + kn + ak);
        }
        __syncthreads();
#pragma unroll
        for (int half = 0; half < 2; half++) {
            bf8_t b = *(const bf8_t*)&Bs[(wn + l16) * BSTR + half * 32 +
                                         quad * 8];
#pragma unroll
            for (int fi = 0; fi < 4; fi++) {
                bf8_t a = *(const bf8_t*)&As[(fi * 16 + l16) * ASTR +
                                             half * 32 + quad * 8];
                acc[fi] = __builtin_amdgcn_mfma_f32_16x16x32_bf16(a, b,
                                                                  acc[fi],
                                                                  0, 0, 0);
            }
        }
    }
    const void* Bias = g.Bias[slot];
    float scale = g.scale[slot];
    float* O = g.Out[slot];
    short* Ob = g.OutBf[slot];
    int n = nb + wn + l16;
    float bia = ldany(Bias, n, isbf);
#pragma unroll
    for (int fi = 0; fi < 4; fi++) {
#pragma unroll
        for (int r = 0; r < 4; r++) {
            int m = mb + fi * 16 + quad * 4 + r;
            float v = (acc[fi][r] + bia) * scale;
            if (relu) v = fmaxf(v, 0.f);
            if (Res) v += Res[(size_t)m * Nper + n];
            if (ResAny) v += ldany(ResAny, (size_t)m * Nper + n, isbf);
            if (O) O[(size_t)m * Nper + n] = v;
            if (Ob) Ob[(size_t)m * Nper + n] = f2b(v);
        }
    }
}

// ---------------------------------------------------------------- pattn
__global__ __launch_bounds__(256) void k_pattn(const float* __restrict__ pcp,
                                               const float* __restrict__ pqp,
                                               float* __restrict__ pattn) {
    __shared__ float pcs[8][65];
    __shared__ float pqs[32][65];
    int bh = blockIdx.y, tb = blockIdx.x;
    int b = bh >> 3, h = bh & 7;
    for (int lin = threadIdx.x; lin < 512; lin += 256) {
        int tt = lin >> 6, dd = lin & 63;
        pcs[tt][dd] = pcp[((size_t)b * 1024 + tb * 8 + tt) * 512 + h * 64 + dd];
    }
    for (int lin = threadIdx.x; lin < 2048; lin += 256) {
        int e = lin >> 6, dd = lin & 63;
        pqs[e][dd] = pqp[(size_t)(b * 32 + e) * 512 + h * 64 + dd];
    }
    __syncthreads();
    int e = threadIdx.x & 31, tt = threadIdx.x >> 5;
    float s = 0.f;
#pragma unroll
    for (int dd = 0; dd < 64; dd++) s += pcs[tt][dd] * pqs[e][dd];
    float r = (s > 0.f) ? (s + log2f(1.f + exp2f(-s))) : log2f(1.f + exp2f(s));
    pattn[((size_t)bh * 1024 + tb * 8 + tt) * 32 + e] = r;
}

// ---------------------------------------------------------------- ECA phase 1
__global__ __launch_bounds__(256) void k_eca1(
    const float* __restrict__ kp, const float* __restrict__ vp,
    const float* __restrict__ pattn, float* __restrict__ L1,
    float* __restrict__ L2) {
    __shared__ float Ks[64][65];
    __shared__ float Vs[64][65];
    __shared__ float Ps[64][33];
    int bh = blockIdx.y, c = blockIdx.x;
    int b = bh >> 3, h = bh & 7;
    size_t rowbase = (size_t)b * 1024 + c * 64;
    for (int ch = threadIdx.x; ch < 1024; ch += 256) {
        int s = ch >> 4, d4 = (ch & 15) * 4;
        size_t gidx = (rowbase + s) * 512 + h * 64 + d4;
        float4 k4 = *(const float4*)&kp[gidx];
        float4 v4 = *(const float4*)&vp[gidx];
        Ks[s][d4] = k4.x; Ks[s][d4 + 1] = k4.y;
        Ks[s][d4 + 2] = k4.z; Ks[s][d4 + 3] = k4.w;
        Vs[s][d4] = v4.x; Vs[s][d4 + 1] = v4.y;
        Vs[s][d4 + 2] = v4.z; Vs[s][d4 + 3] = v4.w;
    }
    for (int ch = threadIdx.x; ch < 512; ch += 256) {
        int s = ch >> 3, e4 = (ch & 7) * 4;
        float4 p4 = *(const float4*)&pattn[((size_t)bh * 1024 + c * 64 + s) * 32 + e4];
        Ps[s][e4] = p4.x; Ps[s][e4 + 1] = p4.y;
        Ps[s][e4 + 2] = p4.z; Ps[s][e4 + 3] = p4.w;
    }
    __syncthreads();
    size_t lbase = ((size_t)bh * 16 + c) * 2048;
    {
        int e = threadIdx.x & 31, dd0 = (threadIdx.x >> 5) * 8;
        float acc[8] = {};
        for (int s = 0; s < 64; s++) {
            float ps = Ps[s][e];
#pragma unroll
            for (int j = 0; j < 8; j++) acc[j] += Ks[s][dd0 + j] * ps;
        }
#pragma unroll
        for (int j = 0; j < 8; j++) L1[lbase + (dd0 + j) * 32 + e] = acc[j];
    }
    {
        int dd = threadIdx.x & 63, e0 = (threadIdx.x >> 6) * 8;
        float acc[8] = {};
        for (int s = 0; s < 64; s++) {
            float vv = Vs[s][dd];
#pragma unroll
            for (int j = 0; j < 8; j++) acc[j] += Ps[s][e0 + j] * vv;
        }
#pragma unroll
        for (int j = 0; j < 8; j++) L2[lbase + (e0 + j) * 64 + dd] = acc[j];
    }
}

// ---------------------------------------------------------------- chunk scan
__global__ __launch_bounds__(256) void k_scan(float* __restrict__ L1,
                                              float* __restrict__ L2) {
    int gid = blockIdx.x * 256 + threadIdx.x;  // 32768 = 16 bh * 2048
    int bh = gid >> 11, lin = gid & 2047;
    size_t base = (size_t)bh * 16 * 2048 + lin;
    float run = 0.f;
#pragma unroll
    for (int c = 0; c < 16; c++) {
        float v = L1[base + c * 2048];
        L1[base + c * 2048] = run;
        run += v;
    }
    run = 0.f;
#pragma unroll
    for (int c = 0; c < 16; c++) {
        float v = L2[base + c * 2048];
        L2[base + c * 2048] = run;
        run += v;
    }
}

// ---------------------------------------------------------------- ECA phase 3
__global__ __launch_bounds__(512) void k_eca3(
    const float* __restrict__ qp, const float* __restrict__ kp,
    const float* __restrict__ vp, const float* __restrict__ pattn,
    const float* __restrict__ L1s, const float* __restrict__ L2s,
    short* __restrict__ attnbf) {
    __shared__ float R0[64][65];
    __shared__ float R1[64][65];
    __shared__ float Ps[64][33];
    __shared__ float SS[2112];
    __shared__ float Pr[64][33];
    int bh = blockIdx.y, c = blockIdx.x;
    int b = bh >> 3, h = bh & 7;
    size_t rowbase = (size_t)b * 1024 + c * 64;
    int tid = threadIdx.x;
    for (int ch = tid; ch < 1024; ch += 512) {
        int t = ch >> 4, d4 = (ch & 15) * 4;
        size_t gidx = (rowbase + t) * 512 + h * 64 + d4;
        float4 q4 = *(const float4*)&qp[gidx];
        float4 k4 = *(const float4*)&kp[gidx];
        R0[t][d4] = q4.x; R0[t][d4 + 1] = q4.y;
        R0[t][d4 + 2] = q4.z; R0[t][d4 + 3] = q4.w;
        R1[t][d4] = k4.x; R1[t][d4 + 1] = k4.y;
        R1[t][d4 + 2] = k4.z; R1[t][d4 + 3] = k4.w;
    }
    if (tid < 512) {
        int ch = tid;
        {
            int t = ch >> 3, e4 = (ch & 7) * 4;
            float4 p4 = *(const float4*)&pattn[((size_t)bh * 1024 + c * 64 + t) * 32 + e4];
            Ps[t][e4] = p4.x; Ps[t][e4 + 1] = p4.y;
            Ps[t][e4 + 2] = p4.z; Ps[t][e4 + 3] = p4.w;
        }
        {
            float4 s4 = *(const float4*)&L1s[((size_t)bh * 16 + c) * 2048 + ch * 4];
            int dd = ch >> 3, e4 = (ch & 7) * 4;
            SS[dd * 33 + e4] = s4.x; SS[dd * 33 + e4 + 1] = s4.y;
            SS[dd * 33 + e4 + 2] = s4.z; SS[dd * 33 + e4 + 3] = s4.w;
        }
    }
    __syncthreads();
    int tx = tid & 15, ty = tid >> 4;
    float a1r[2][4] = {};
    float qs1[2][2] = {};
    for (int dd = 0; dd < 64; dd++) {
        float q2[2], k4[4];
#pragma unroll
        for (int i = 0; i < 2; i++) q2[i] = R0[ty * 2 + i][dd];
#pragma unroll
        for (int j = 0; j < 4; j++) k4[j] = R1[tx * 4 + j][dd];
#pragma unroll
        for (int i = 0; i < 2; i++)
#pragma unroll
            for (int j = 0; j < 4; j++) a1r[i][j] += q2[i] * k4[j];
        float s1a = SS[dd * 33 + tx * 2], s1b = SS[dd * 33 + tx * 2 + 1];
#pragma unroll
        for (int i = 0; i < 2; i++) {
            qs1[i][0] += q2[i] * s1a;
            qs1[i][1] += q2[i] * s1b;
        }
    }
    __syncthreads();
#pragma unroll
    for (int i = 0; i < 2; i++) {
#pragma unroll
        for (int j = 0; j < 4; j++) R0[ty * 2 + i][tx * 4 + j] = a1r[i][j];
        Pr[ty * 2 + i][tx * 2] = qs1[i][0];
        Pr[ty * 2 + i][tx * 2 + 1] = qs1[i][1];
    }
    for (int ch = tid; ch < 1024; ch += 512) {
        int t = ch >> 4, d4 = (ch & 15) * 4;
        float4 v4 = *(const float4*)&vp[(rowbase + t) * 512 + h * 64 + d4];
        R1[t][d4] = v4.x; R1[t][d4 + 1] = v4.y;
        R1[t][d4 + 2] = v4.z; R1[t][d4 + 3] = v4.w;
    }
    __syncthreads();
    {
        int e = tid & 31, t0 = (tid >> 5) * 4;
        for (int k2 = 0; k2 < 4; k2++) {
            int t = t0 + k2;
            float s = Pr[t][e];
            for (int s2 = 0; s2 <= t; s2++) s += R0[t][s2] * Ps[s2][e];
            Pr[t][e] = s / (float)(c * 64 + t + 1);
        }
    }
    __syncthreads();
    if (tid < 64) {
        float m = -1e30f;
        for (int e = 0; e < 32; e++) m = fmaxf(m, Pr[tid][e]);
        float sum = 0.f;
        for (int e = 0; e < 32; e++) {
            float ex = expf(Pr[tid][e] - m);
            Pr[tid][e] = ex;
            sum += ex;
        }
        float inv = 1.f / sum;
        for (int e = 0; e < 32; e++) Pr[tid][e] *= inv;
    } else if (tid >= 128) {
        for (int ch = tid - 128; ch < 512; ch += 384) {
            float4 s4 = *(const float4*)&L2s[((size_t)bh * 16 + c) * 2048 + ch * 4];
            int e = ch >> 4, d4 = (ch & 15) * 4;
            SS[e * 65 + d4] = s4.x; SS[e * 65 + d4 + 1] = s4.y;
            SS[e * 65 + d4 + 2] = s4.z; SS[e * 65 + d4 + 3] = s4.w;
        }
    }
    __syncthreads();
    float a2r[2][4] = {};
    float ps2[2][4] = {};
    for (int e = 0; e < 32; e++) {
        float p2[2], b4[4], v4[4];
#pragma unroll
        for (int i = 0; i < 2; i++) p2[i] = Pr[ty * 2 + i][e];
#pragma unroll
        for (int j = 0; j < 4; j++) {
            b4[j] = Ps[tx * 4 + j][e];
            v4[j] = SS[e * 65 + tx * 4 + j];
        }
#pragma unroll
        for (int i = 0; i < 2; i++)
#pragma unroll
            for (int j = 0; j < 4; j++) {
                a2r[i][j] += p2[i] * b4[j];
                ps2[i][j] += p2[i] * v4[j];
            }
    }
    __syncthreads();
#pragma unroll
    for (int i = 0; i < 2; i++)
#pragma unroll
        for (int j = 0; j < 4; j++) R0[ty * 2 + i][tx * 4 + j] = a2r[i][j];
    __syncthreads();
#pragma unroll
    for (int i = 0; i < 2; i++) {
        int t = ty * 2 + i;
        float acch[4];
#pragma unroll
        for (int j = 0; j < 4; j++) acch[j] = ps2[i][j];
        for (int s = 0; s <= t; s++) {
            float a2v = R0[t][s];
#pragma unroll
            for (int j = 0; j < 4; j++) acch[j] += a2v * R1[s][tx * 4 + j];
        }
        float inv = 1.f / (float)(c * 64 + t + 1);
        short4 o;
        o.x = f2b(acch[0] * inv); o.y = f2b(acch[1] * inv);
        o.z = f2b(acch[2] * inv); o.w = f2b(acch[3] * inv);
        *(short4*)&attnbf[(rowbase + t) * 512 + h * 64 + tx * 4] = o;
    }
}

// ---------------------------------------------------------------- MHA1 scores
__global__ __launch_bounds__(256) void k_mha1_scores(
    const float* __restrict__ pkq, const float* __restrict__ pkk,
    float* __restrict__ sbuf) {
    __shared__ float Qs[32][65];
    __shared__ float Ks[64][65];
    int bh = blockIdx.y, kb = blockIdx.x;
    int b = bh >> 3, h = bh & 7;
    for (int lin = threadIdx.x; lin < 2048; lin += 256) {
        int i = lin >> 6, dd = lin & 63;
        Qs[i][dd] = pkq[(size_t)(b * 32 + i) * 512 + h * 64 + dd];
    }
    for (int lin = threadIdx.x; lin < 4096; lin += 256) {
        int kk = lin >> 6, dd = lin & 63;
        Ks[kk][dd] = pkk[((size_t)b * 1024 + kb * 64 + kk) * 512 + h * 64 + dd];
    }
    __syncthreads();
    int kk = threadIdx.x & 63, i0 = (threadIdx.x >> 6) * 8;
    for (int ii = 0; ii < 8; ii++) {
        int i = i0 + ii;
        float s = 0.f;
#pragma unroll
        for (int dd = 0; dd < 64; dd++) s += Qs[i][dd] * Ks[kk][dd];
        sbuf[((size_t)bh * 32 + i) * 1024 + kb * 64 + kk] = s;
    }
}

// ---------------------------------------------------------------- row softmax
__global__ __launch_bounds__(256) void k_softmax_rows(float* __restrict__ buf,
                                                      int cols) {
    int wave = threadIdx.x >> 6, lane = threadIdx.x & 63;
    int row = blockIdx.x * 4 + wave;
    float* p = buf + (size_t)row * cols;
    int per = cols >> 6;
    float m = -1e30f;
    for (int j = 0; j < per; j++) m = fmaxf(m, p[lane + 64 * j]);
#pragma unroll
    for (int off = 32; off >= 1; off >>= 1) m = fmaxf(m, __shfl_xor(m, off, 64));
    float sum = 0.f;
    for (int j = 0; j < per; j++) {
        float ex = expf(p[lane + 64 * j] - m);
        p[lane + 64 * j] = ex;
        sum += ex;
    }
#pragma unroll
    for (int off = 32; off >= 1; off >>= 1) sum += __shfl_xor(sum, off, 64);
    float inv = 1.f / sum;
    for (int j = 0; j < per; j++) p[lane + 64 * j] *= inv;
}

// ---------------------------------------------------------------- MHA1 ctx
__global__ __launch_bounds__(256) void k_mha1_ctx_p(
    const float* __restrict__ sbuf, const float* __restrict__ pkv,
    float* __restrict__ part) {
    __shared__ float Vs[64][65];
    __shared__ float Ps[32][33];
    int bh = blockIdx.y, c = blockIdx.x;
    int b = bh >> 3, h = bh & 7;
    for (int lin = threadIdx.x; lin < 4096; lin += 256) {
        int kk = lin >> 6, dd = lin & 63;
        Vs[kk][dd] = pkv[((size_t)b * 1024 + c * 64 + kk) * 512 + h * 64 + dd];
    }
    for (int lin = threadIdx.x; lin < 2048; lin += 256) {
        int i = lin >> 6, kk = lin & 63;
        Ps[i][kk] = sbuf[((size_t)bh * 32 + i) * 1024 + c * 64 + kk];
    }
    __syncthreads();
    int dd = threadIdx.x & 63, ig = threadIdx.x >> 6;
    float acc[8] = {};
    for (int kk = 0; kk < 64; kk++) {
        float vv = Vs[kk][dd];
#pragma unroll
        for (int j = 0; j < 8; j++) acc[j] += Ps[ig * 8 + j][kk] * vv;
    }
    size_t base = ((size_t)bh * 16 + c) * 2048;
#pragma unroll
    for (int j = 0; j < 8; j++) part[base + (ig * 8 + j) * 64 + dd] = acc[j];
}

__global__ __launch_bounds__(256) void k_mha1_ctx_r(
    const float* __restrict__ part, float* __restrict__ yp_raw,
    short* __restrict__ yp_bf) {
    int gid = blockIdx.x * 256 + threadIdx.x;
    int bh = gid >> 11, rem = gid & 2047;
    int i = rem >> 6, dd = rem & 63;
    float s = 0.f;
#pragma unroll
    for (int c = 0; c < 16; c++) s += part[((size_t)bh * 16 + c) * 2048 + rem];
    int b = bh >> 3, h = bh & 7;
    size_t o = (size_t)(b * 32 + i) * 512 + h * 64 + dd;
    yp_raw[o] = s;
    yp_bf[o] = f2b(s);
}

// ---------------------------------------------------------------- MHA2 (fused)
__global__ __launch_bounds__(256) void k_mha2(const float* __restrict__ upq,
                                              const float* __restrict__ upk,
                                              const float* __restrict__ upv,
                                              short* __restrict__ yxbf) {
    __shared__ float Ksm[32][65];
    __shared__ float Vsm[32][65];
    __shared__ float Qsm[64][65];
    __shared__ float Prm[64][33];
    int bh = blockIdx.y, c = blockIdx.x;
    int b = bh >> 3, h = bh & 7;
    for (int lin = threadIdx.x; lin < 2048; lin += 256) {
        int e = lin >> 6, dd = lin & 63;
        Ksm[e][dd] = upk[(size_t)(b * 32 + e) * 512 + h * 64 + dd];
        Vsm[e][dd] = upv[(size_t)(b * 32 + e) * 512 + h * 64 + dd];
    }
    for (int lin = threadIdx.x; lin < 4096; lin += 256) {
        int t = lin >> 6, dd = lin & 63;
        Qsm[t][dd] = upq[((size_t)b * 1024 + c * 64 + t) * 512 + h * 64 + dd];
    }
    __syncthreads();
    int row = threadIdx.x >> 2, r = threadIdx.x & 3;
    float p[8];
#pragma unroll
    for (int j = 0; j < 8; j++) {
        int e = r * 8 + j;
        float s = 0.f;
#pragma unroll
        for (int dd = 0; dd < 64; dd++) s += Qsm[row][dd] * Ksm[e][dd];
        p[j] = s;
    }
    float m = -1e30f;
#pragma unroll
    for (int j = 0; j < 8; j++) m = fmaxf(m, p[j]);
    m = fmaxf(m, __shfl_xor(m, 1, 64));
    m = fmaxf(m, __shfl_xor(m, 2, 64));
    float sum = 0.f;
#pragma unroll
    for (int j = 0; j < 8; j++) {
        p[j] = expf(p[j] - m);
        sum += p[j];
    }
    sum += __shfl_xor(sum, 1, 64);
    sum += __shfl_xor(sum, 2, 64);
    float inv = 1.f / sum;
#pragma unroll
    for (int j = 0; j < 8; j++) Prm[row][r * 8 + j] = p[j] * inv;
    __syncthreads();
    for (int j4 = 0; j4 < 4; j4++) {
        short4 o;
        float a4[4];
#pragma unroll
        for (int q = 0; q < 4; q++) {
            int dd = r * 16 + j4 * 4 + q;
            float acc = 0.f;
#pragma unroll
            for (int e = 0; e < 32; e++) acc += Prm[row][e] * Vsm[e][dd];
            a4[q] = acc;
        }
        o.x = f2b(a4[0]); o.y = f2b(a4[1]);
        o.z = f2b(a4[2]); o.w = f2b(a4[3]);
        *(short4*)&yxbf[((size_t)b * 1024 + c * 64 + row) * 512 + h * 64 +
                        r * 16 + j4 * 4] = o;
    }
}

// ---------------------------------------------------------------- LayerNorm
__global__ __launch_bounds__(256) void k_ln(
    const float* __restrict__ x, const float* __restrict__ residf,
    const void* __restrict__ residany, const void* __restrict__ gv,
    const void* __restrict__ bv, float* __restrict__ out32,
    short* __restrict__ dupbf, void* __restrict__ outany, size_t ooff,
    const int* __restrict__ flagp) {
    int isbf = *flagp;
    int wave = threadIdx.x >> 6, lane = threadIdx.x & 63;
    int row = blockIdx.x * 4 + wave;
    const float* px = x + (size_t)row * 512;
    float v[8];
#pragma unroll
    for (int j = 0; j < 8; j++) {
        int col = lane + 64 * j;
        v[j] = px[col];
        if (residf) v[j] += residf[(size_t)row * 512 + col];
        if (residany) v[j] += ldany(residany, (size_t)row * 512 + col, isbf);
    }
    float sum = 0.f;
#pragma unroll
    for (int j = 0; j < 8; j++) sum += v[j];
#pragma unroll
    for (int off = 32; off >= 1; off >>= 1) sum += __shfl_xor(sum, off, 64);
    float mean = sum * (1.f / 512.f);
    float var = 0.f;
#pragma unroll
    for (int j = 0; j < 8; j++) {
        float d = v[j] - mean;
        var += d * d;
    }
#pragma unroll
    for (int off = 32; off >= 1; off >>= 1) var += __shfl_xor(var, off, 64);
    var *= (1.f / 512.f);
    float inv = rsqrtf(var + 1e-5f);
#pragma unroll
    for (int j = 0; j < 8; j++) {
        int col = lane + 64 * j;
        float y = (v[j] - mean) * inv * ldany(gv, col, isbf) +
                  ldany(bv, col, isbf);
        size_t oidx = (size_t)row * 512 + col;
        if (out32) out32[oidx] = y;
        if (dupbf) dupbf[oidx] = f2b(y);
        if (outany) {
            if (isbf)
                ((bf16*)outany + ooff)[oidx] = __float2bfloat16(y);
            else
                ((float*)outany + ooff)[oidx] = y;
        }
    }
}

// ================================================================ launch
extern "C" void kernel_launch(void* const* d_in, const int* in_sizes, int n_in,
                              void* d_out, int out_size, void* d_ws,
                              size_t ws_size, hipStream_t stream) {
    (void)in_sizes; (void)n_in; (void)out_size; (void)ws_size;
    const void* dec_in = d_in[0];
    const void* p_in = d_in[1];
    const void* enc_in = d_in[2];

    const size_t M1 = 1048576;
    float* ws = (float*)d_ws;
    float* A_ = ws + 0 * M1;  // sa_q proj (fp32) -> yx2 fp32 (final resid)
    float* B_ = ws + 1 * M1;  // sa_k -> pk_k ; B_..C_ -> ff1_bf (4M shorts)
    float* C_ = ws + 2 * M1;  // sa_v -> pk_v -> up_q (fp32, mha2 reads)
    float* D_ = ws + 3 * M1;  // sa_pc -> ca_lin out (fp32, k_ln x)
    float* E_ = ws + 4 * M1;  // bf16 zone: attn_bf / mha2ctx_bf
    float* F_ = ws + 5 * M1;  // sa_out+resid fp32 -> ff2 out fp32
    float* S_ = ws + 6 * M1;  // scratch
    float* pattn = S_;                  // 512K (-> sbuf)
    float* L1 = S_ + 524288;            // 512K
    float* L2 = S_ + 1048576;           // 512K (-> part)
    float* pqp = S_ + 1572864;          // 32K
    float* pkq = S_ + 1605632;          // 32K
    float* ypraw = S_ + 1638400;        // 32K
    float* upk = S_ + 1671168;          // 32K
    float* upv = S_ + 1703936;          // 32K
    float* sbuf = S_;                   // alias pattn (dead after eca3)
    float* part = S_ + 1048576;         // alias L2 (dead after scan+eca3)
    int* flagp = (int*)(S_ + 1736704);
    // bf16 buffers (shorts)
    short* attn_bf = (short*)E_;                  // 1M sh
    short* mha2_bf = (short*)(E_ + 524288);       // 1M sh
    short* ff1_bf = (short*)B_;                   // 4M sh spanning B_..C_
    short* dec_bf = (short*)(ws + 7 * M1 + 786432);   // 1M sh
    short* enc_bf = dec_bf + M1;                  // 1M sh
    short* p_bf = enc_bf + M1;                    // 32K sh
    short* F_bf = p_bf + 32768;                   // 1M sh
    short* yp_bf = F_bf + M1;                     // 32K sh
    short* yx2_bf = yp_bf + 32768;                // 1M sh
    short* wt = yx2_bf + M1;                      // 13*256K sh
    short* ff1t = wt + 13 * 262144;               // 1M sh
    short* ff2t = ff1t + M1;                      // 1M sh  (total ~50 MB)
    auto WTp = [&](int wi) { return wt + (size_t)((wi - 6) / 2) * 262144; };

    hipStream_t S = stream;
    k_detect<<<1, 64, 0, S>>>(dec_in, flagp);
    k_tobf<<<4096, 256, 0, S>>>(dec_in, dec_bf, 1048576, flagp);
    k_tobf<<<4096, 256, 0, S>>>(enc_in, enc_bf, 1048576, flagp);
    k_tobf<<<128, 256, 0, S>>>(p_in, p_bf, 32768, flagp);
    {
        WT13 w13;
        for (int s = 0; s < 13; s++) w13.src[s] = d_in[6 + 2 * s];
        k_wtrans<<<dim3(16, 16, 13), 256, 0, S>>>(w13, wt, 512, 512, flagp);
        WT13 w1;
        w1.src[0] = d_in[38];
        k_wtrans<<<dim3(64, 16, 1), 256, 0, S>>>(w1, ff1t, 512, 2048, flagp);
        WT13 w2;
        w2.src[0] = d_in[40];
        k_wtrans<<<dim3(16, 64, 1), 256, 0, S>>>(w2, ff2t, 2048, 512, flagp);
    }

    auto Bv = [&](int i) { return (const void*)d_in[i]; };
    auto mf = [&](const short* A, GArgs g, const float* res,
                  const void* resany, int M, int Ncat, int Nper, int K,
                  int relu) {
        dim3 grid((unsigned)(Ncat / 64), (unsigned)(M / 64));
        k_gemm_mfma<<<grid, 256, 0, S>>>(A, g, res, resany, Nper, K, relu,
                                         flagp);
    };
    short* nb16 = nullptr;
    float* nf32 = nullptr;

    // --- self attention projections (fused: q, pc, k, v share A=dec) ---
    {
        GArgs g = {{WTp(6), WTp(10), WTp(12), WTp(14)},
                   {Bv(7), Bv(11), Bv(13), Bv(15)},
                   {0.125f, 1.f, 1.f, 1.f},
                   {A_, D_, B_, C_},
                   {nb16, nb16, nb16, nb16}};
        mf(dec_bf, g, nullptr, nullptr, 2048, 2048, 512, 512, 0);
    }
    // --- p projections (fused: sa_pq + pk_q) ---
    {
        GArgs g = {{WTp(8), WTp(18), WTp(8), WTp(8)},
                   {Bv(9), Bv(19), Bv(9), Bv(9)},
                   {0.125f, 0.125f, 0.f, 0.f},
                   {pqp, pkq, pqp, pqp},
                   {nb16, nb16, nb16, nb16}};
        mf(p_bf, g, nullptr, nullptr, 64, 1024, 512, 512, 0);
    }
    k_pattn<<<dim3(128, 16), 256, 0, S>>>(D_, pqp, pattn);
    k_eca1<<<dim3(16, 16), 256, 0, S>>>(B_, C_, pattn, L1, L2);
    k_scan<<<128, 256, 0, S>>>(L1, L2);
    k_eca3<<<dim3(16, 16), 512, 0, S>>>(A_, B_, C_, pattn, L1, L2, attn_bf);
    {  // sa_out + residual(dec): fp32 F_ (LN resid) + bf16 F_bf (up_q A)
        GArgs g = {{WTp(16), WTp(16), WTp(16), WTp(16)},
                   {Bv(17), Bv(17), Bv(17), Bv(17)},
                   {1.f, 1.f, 1.f, 1.f},
                   {F_, F_, F_, F_},
                   {F_bf, F_bf, F_bf, F_bf}};
        mf(attn_bf, g, nullptr, dec_in, 2048, 512, 512, 512, 0);
    }

    // --- cross attention: Yp = MHA(p, enc, enc) ---
    {  // pk_k + pk_v fused (A=enc)
        GArgs g = {{WTp(20), WTp(22), WTp(20), WTp(20)},
                   {Bv(21), Bv(23), Bv(21), Bv(21)},
                   {1.f, 1.f, 1.f, 1.f},
                   {B_, C_, B_, B_},
                   {nb16, nb16, nb16, nb16}};
        mf(enc_bf, g, nullptr, nullptr, 2048, 1024, 512, 512, 0);
    }
    k_mha1_scores<<<dim3(16, 16), 256, 0, S>>>(pkq, B_, sbuf);
    k_softmax_rows<<<512 / 4, 256, 0, S>>>(sbuf, 1024);
    k_mha1_ctx_p<<<dim3(16, 16), 256, 0, S>>>(sbuf, C_, part);
    k_mha1_ctx_r<<<128, 256, 0, S>>>(part, ypraw, yp_bf);

    // --- Yx = MHA(dec, Yp_raw, Yp_raw) ---
    {  // up_k + up_v fused (A=ypraw)
        GArgs g = {{WTp(26), WTp(28), WTp(26), WTp(26)},
                   {Bv(27), Bv(29), Bv(27), Bv(27)},
                   {1.f, 1.f, 1.f, 1.f},
                   {upk, upv, upk, upk},
                   {nb16, nb16, nb16, nb16}};
        mf(yp_bf, g, nullptr, nullptr, 64, 1024, 512, 512, 0);
    }
    {  // up_q (scaled)
        GArgs g = {{WTp(24), WTp(24), WTp(24), WTp(24)},
                   {Bv(25), Bv(25), Bv(25), Bv(25)},
                   {0.125f, 0.125f, 0.125f, 0.125f},
                   {C_, C_, C_, C_},
                   {nb16, nb16, nb16, nb16}};
        mf(F_bf, g, nullptr, nullptr, 2048, 512, 512, 512, 0);
    }
    // Yp output = LN(Yp_raw + p)
    k_ln<<<64 / 4, 256, 0, S>>>(ypraw, nullptr, p_in, d_in[32], d_in[33],
                                nullptr, nullptr, d_out, 1048576, flagp);
    k_mha2<<<dim3(16, 16), 256, 0, S>>>(C_, upk, upv, mha2_bf);
    {  // ca_lin
        GArgs g = {{WTp(30), WTp(30), WTp(30), WTp(30)},
                   {Bv(31), Bv(31), Bv(31), Bv(31)},
                   {1.f, 1.f, 1.f, 1.f},
                   {D_, D_, D_, D_},
                   {nb16, nb16, nb16, nb16}};
        mf(mha2_bf, g, nullptr, nullptr, 2048, 512, 512, 512, 0);
    }
    k_ln<<<2048 / 4, 256, 0, S>>>(D_, F_, nullptr, d_in[34], d_in[35], A_,
                                  yx2_bf, nullptr, 0, flagp);  // yx2

    // --- FFN ---
    {  // ff1 + relu -> bf16 only (sole consumer is ff2 GEMM)
        GArgs g = {{ff1t, ff1t, ff1t, ff1t},
                   {Bv(39), Bv(39), Bv(39), Bv(39)},
                   {1.f, 1.f, 1.f, 1.f},
                   {nf32, nf32, nf32, nf32},
                   {ff1_bf, ff1_bf, ff1_bf, ff1_bf}};
        mf(yx2_bf, g, nullptr, nullptr, 2048, 2048, 2048, 512, 1);
    }
    {  // ff2
        GArgs g = {{ff2t, ff2t, ff2t, ff2t},
                   {Bv(41), Bv(41), Bv(41), Bv(41)},
                   {1.f, 1.f, 1.f, 1.f},
                   {F_, F_, F_, F_},
                   {nb16, nb16, nb16, nb16}};
        mf(ff1_bf, g, nullptr, nullptr, 2048, 512, 512, 2048, 0);
    }
    k_ln<<<2048 / 4, 256, 0, S>>>(F_, A_, nullptr, d_in[36], d_in[37],
                                  nullptr, nullptr, d_out, 0, flagp);
}